// Round 3
// baseline (1483.748 us; speedup 1.0000x reference)
//
#include <hip/hip_runtime.h>
#include <hip/hip_bf16.h>
#include <stdint.h>

typedef __hip_bfloat16 bf16;
typedef unsigned long long ull;
#define NT 256

__device__ __forceinline__ float b2f(bf16 v){ return __bfloat162float(v); }
__device__ __forceinline__ bf16 f2b(float v){ return __float2bfloat16(v); }
__device__ __forceinline__ float lrelu(float a){ return a>0.f ? a : 0.2f*a; }
__device__ __forceinline__ float sanf(float v){ return __builtin_isfinite(v) ? v : -12345.f; }
__device__ __forceinline__ float us2f(unsigned short u){ return __uint_as_float(((unsigned)u)<<16); }
__device__ __forceinline__ unsigned short f2bu(float v){ bf16 b=f2b(v); unsigned short u; __builtin_memcpy(&u,&b,2); return u; }

// dtype-flexible input load: f32in ? float : bf16
__device__ __forceinline__ float ld(const void* p, size_t i, int f32in){
  return f32in ? ((const float*)p)[i] : b2f(((const bf16*)p)[i]);
}

__device__ __forceinline__ float waveReduceSum(float v){
#pragma unroll
  for(int o=32;o>0;o>>=1) v += __shfl_down(v,o,64);
  return v;
}

__device__ __forceinline__ unsigned clampi(int v, int n){
  unsigned u=(unsigned)v; return (u<(unsigned)n)?u:0u;
}

// vectorized bf16 h1 row load (16 ch = 4x 8B)
__device__ __forceinline__ void load_h1v(const bf16* h1, unsigned node, float* dst){
  const ull* p=(const ull*)(h1+(size_t)node*16);
#pragma unroll
  for(int q=0;q<4;q++){
    ull v=p[q];
    dst[q*4+0]=us2f((unsigned short)v);        dst[q*4+1]=us2f((unsigned short)(v>>16));
    dst[q*4+2]=us2f((unsigned short)(v>>32));  dst[q*4+3]=us2f((unsigned short)(v>>48));
  }
}
// x row (4 ch) load, dtype-flex
__device__ __forceinline__ void load_x4(const void* x, unsigned n, int f32in, float* o){
  if(f32in){ float4 v=((const float4*)x)[n]; o[0]=v.x;o[1]=v.y;o[2]=v.z;o[3]=v.w; }
  else{
    ull v=((const ull*)x)[n];
    o[0]=us2f((unsigned short)v);       o[1]=us2f((unsigned short)(v>>16));
    o[2]=us2f((unsigned short)(v>>32)); o[3]=us2f((unsigned short)(v>>48));
  }
}

// ---------------- K0: zero stats, detect input dtype -> ((int*)stats)[7]
__global__ __launch_bounds__(64) void k_probe(const unsigned short* __restrict__ xraw,
                                              int nscan, float* __restrict__ stats){
  int t=threadIdx.x;
  int bad=0;
  for(int k=t*8;k<t*8+8;k++){
    if(k<nscan){
      unsigned short u=xraw[k];
      unsigned ex=(u>>7)&0xFF;
      bool plaus = (ex==0u) || (ex>=97u && ex<=157u);
      if(!plaus) bad++;
    }
  }
#pragma unroll
  for(int o=32;o>0;o>>=1) bad += __shfl_down(bad,o,64);
  if(t==0){
    for(int i=0;i<7;i++) stats[i]=0.f;
    ((int*)stats)[7] = (bad>=8) ? 1 : 0;
  }
}

// ---------------- K1: histogram of destinations + edge_attr sums -> stats[0..2]
__global__ __launch_bounds__(NT) void k_prep(const void* __restrict__ ea,
                                             const int* __restrict__ idx,
                                             int* __restrict__ rowc,
                                             float* __restrict__ stats, int E, int N){
  const int f32in=((const int*)stats)[7];
  __shared__ float lds[16];
  float s0=0.f,s1=0.f,s2=0.f;
  for(size_t e=(size_t)blockIdx.x*NT+threadIdx.x; e<(size_t)E; e+=(size_t)gridDim.x*NT){
    s0+=ld(ea,e*3+0,f32in); s1+=ld(ea,e*3+1,f32in); s2+=ld(ea,e*3+2,f32in);
    unsigned d=clampi(idx[(size_t)E+e],N);
    atomicAdd(&rowc[d],1);
  }
  int lane=threadIdx.x&63, wv=threadIdx.x>>6;
  s0=waveReduceSum(s0); s1=waveReduceSum(s1); s2=waveReduceSum(s2);
  if(lane==0){ lds[wv*4+0]=s0; lds[wv*4+1]=s1; lds[wv*4+2]=s2; }
  __syncthreads();
  if(threadIdx.x==0){
    float a0=0,a1=0,a2=0;
    for(int w=0;w<NT/64;w++){ a0+=lds[w*4]; a1+=lds[w*4+1]; a2+=lds[w*4+2]; }
    atomicAdd(&stats[0],a0); atomicAdd(&stats[1],a1); atomicAdd(&stats[2],a2);
  }
}

// ---------------- K2: als/ald per node
__global__ __launch_bounds__(NT) void k_node1(
    const void* __restrict__ x, const void* __restrict__ W1,
    const void* __restrict__ as1, const void* __restrict__ ad1,
    const float* __restrict__ stats,
    float* __restrict__ als, float* __restrict__ ald, int N){
  const int f32in=((const int*)stats)[7];
  __shared__ float sW1[64], sas[16], sad[16];
  if(threadIdx.x<64) sW1[threadIdx.x]=ld(W1,threadIdx.x,f32in);
  if(threadIdx.x<16){ sas[threadIdx.x]=ld(as1,threadIdx.x,f32in); sad[threadIdx.x]=ld(ad1,threadIdx.x,f32in); }
  __syncthreads();
  int i=blockIdx.x*NT+threadIdx.x;
  if(i>=N) return;
  float xv[4]; load_x4(x,(unsigned)i,f32in,xv);
  float a_s=0.f,a_d=0.f;
#pragma unroll
  for(int j=0;j<16;j++){
    float v=xv[0]*sW1[j]+xv[1]*sW1[16+j]+xv[2]*sW1[32+j]+xv[3]*sW1[48+j];
    a_s+=v*sas[j]; a_d+=v*sad[j];
  }
  als[i]=a_s; ald[i]=a_d;
}

// ---------------- scan (3 kernels): rowc hist -> exclusive starts
__global__ __launch_bounds__(NT) void k_scan1(const int* __restrict__ rowc, int* __restrict__ bsum, int N){
  __shared__ int sm[NT];
  int i=blockIdx.x*NT+threadIdx.x;
  sm[threadIdx.x]=(i<N)?rowc[i]:0;
  __syncthreads();
  for(int o=NT/2;o>0;o>>=1){ if(threadIdx.x<o) sm[threadIdx.x]+=sm[threadIdx.x+o]; __syncthreads(); }
  if(threadIdx.x==0) bsum[blockIdx.x]=sm[0];
}
__global__ __launch_bounds__(1024) void k_scan2(int* __restrict__ bsum, int NB){
  __shared__ int sm[1024];
  int i=threadIdx.x;
  int v=(i<NB)?bsum[i]:0;
  sm[i]=v; __syncthreads();
  for(int o=1;o<1024;o<<=1){
    int t=(i>=o)?sm[i-o]:0; __syncthreads();
    sm[i]+=t; __syncthreads();
  }
  if(i<NB) bsum[i]=(i==0)?0:sm[i-1];
}
__global__ __launch_bounds__(NT) void k_scan3(int* __restrict__ rowc, const int* __restrict__ bsum, int N){
  __shared__ int sm[NT];
  int i=blockIdx.x*NT+threadIdx.x;
  int v=(i<N)?rowc[i]:0;
  sm[threadIdx.x]=v; __syncthreads();
  for(int o=1;o<NT;o<<=1){
    int t=(threadIdx.x>=o)?sm[threadIdx.x-o]:0; __syncthreads();
    sm[threadIdx.x]+=t; __syncthreads();
  }
  if(i<N) rowc[i]=bsum[blockIdx.x]+sm[threadIdx.x]-v;   // exclusive start
}

// ---------------- K3: scatter packed {src, alpha_partial} into CSR slots; rowc -> end
__global__ __launch_bounds__(NT) void k_scatter(
    const int* __restrict__ idx, const void* __restrict__ ea,
    const void* __restrict__ We1, const void* __restrict__ ae1,
    const float* __restrict__ als, const float* __restrict__ stats,
    int* __restrict__ rowc, ull* __restrict__ csr, int E, int N){
  const int f32in=((const int*)stats)[7];
  __shared__ float sve[3];
  if(threadIdx.x<3){
    float v=0.f;
    for(int j=0;j<16;j++) v+=ld(We1,threadIdx.x*16+j,f32in)*ld(ae1,j,f32in);
    sve[threadIdx.x]=v;
  }
  __syncthreads();
  int e=blockIdx.x*NT+threadIdx.x;
  if(e>=E) return;
  unsigned s=clampi(idx[e],N), d=clampi(idx[(size_t)E+e],N);
  float ap = als[s] + ld(ea,(size_t)e*3+0,f32in)*sve[0]
                    + ld(ea,(size_t)e*3+1,f32in)*sve[1]
                    + ld(ea,(size_t)e*3+2,f32in)*sve[2];
  int pos=atomicAdd(&rowc[d],1);
  csr[pos] = (ull)s | ((ull)__float_as_uint(ap)<<32);
}

// ---------------- K4: gather-aggregate layer-1 softmax; write h1(bf16), h2, als2, ald2
// 16 lanes per node; 4 nodes per wave; 16 nodes per block.
__global__ __launch_bounds__(NT) void k_gather1(
    const ull* __restrict__ csr, const int* __restrict__ rowe,
    const float* __restrict__ als, const float* __restrict__ ald,
    const void* __restrict__ x, const void* __restrict__ W1, const void* __restrict__ b1,
    const void* __restrict__ W2, const void* __restrict__ as2, const void* __restrict__ ad2,
    const void* __restrict__ We1, const void* __restrict__ ae1,
    const float* __restrict__ stats, float invE,
    bf16* __restrict__ h1, float* __restrict__ h2,
    float* __restrict__ als2, float* __restrict__ ald2, int N){
  const int f32in=((const int*)stats)[7];
  __shared__ float sW1[64], sb1[16], sW2[32], sas2[2], sad2[2], saea[1];
  if(threadIdx.x<64) sW1[threadIdx.x]=ld(W1,threadIdx.x,f32in);
  if(threadIdx.x<16) sb1[threadIdx.x]=ld(b1,threadIdx.x,f32in);
  if(threadIdx.x<32) sW2[threadIdx.x]=ld(W2,threadIdx.x,f32in);
  if(threadIdx.x<2){ sas2[threadIdx.x]=ld(as2,threadIdx.x,f32in); sad2[threadIdx.x]=ld(ad2,threadIdx.x,f32in); }
  if(threadIdx.x==0){
    float a=0.f;
    for(int k=0;k<3;k++){
      float v=0.f;
      for(int j=0;j<16;j++) v+=ld(We1,k*16+j,f32in)*ld(ae1,j,f32in);
      a+=stats[k]*v;
    }
    saea[0]=a*invE;
  }
  __syncthreads();
  int n=blockIdx.x*16+(threadIdx.x>>4);
  int c=threadIdx.x&15;
  if(n>=N) return;
  int end=rowe[n];
  int start=(n==0)?0:rowe[n-1];
  float aldn=ald[n], alsn=als[n];
  float aself=lrelu(alsn+aldn+saea[0]);
  float w0=sW1[c], w1=sW1[16+c], w2=sW1[32+c], w3=sW1[48+c];
  // phase A: segment max (strided over slots)
  float m=aself;
  for(int k=start+c;k<end;k+=16){
    float ap=__uint_as_float((unsigned)(csr[k]>>32));
    m=fmaxf(m,lrelu(ap+aldn));
  }
#pragma unroll
  for(int o=1;o<16;o<<=1) m=fmaxf(m,__shfl_xor(m,o,64));
  // self contribution
  float xv[4]; load_x4(x,(unsigned)n,f32in,xv);
  float hc_self=xv[0]*w0+xv[1]*w1+xv[2]*w2+xv[3]*w3;
  float exs=expf(fminf(aself-m,0.f));
  float den=exs, acc=exs*hc_self;
  // phase B: serial over slots, lane c = channel
  for(int k=start;k<end;k++){
    ull v=csr[k];
    unsigned src=(unsigned)(v&0xffffffffu);
    float ap=__uint_as_float((unsigned)(v>>32));
    float ex=expf(fminf(lrelu(ap+aldn)-m,0.f));
    den+=ex;
    float xs[4]; load_x4(x,src,f32in,xs);
    float hc=xs[0]*w0+xs[1]*w1+xs[2]*w2+xs[3]*w3;
    acc+=ex*hc;
  }
  float inv=1.f/(den+1e-16f);
  float h1c=acc*inv+sb1[c];
  h1[(size_t)n*16+c]=f2b(h1c);
  float r0=h1c*sW2[c*2+0], r1=h1c*sW2[c*2+1];
#pragma unroll
  for(int o=1;o<16;o<<=1){ r0+=__shfl_xor(r0,o,64); r1+=__shfl_xor(r1,o,64); }
  if(c==0){
    h2[(size_t)n*2+0]=r0; h2[(size_t)n*2+1]=r1;
    als2[n]=r0*sas2[0]+r1*sas2[1];
    ald2[n]=r0*sad2[0]+r1*sad2[1];
  }
}

// ---------------- K5: normalize all edge-MLP weights to f32 in global gw[1040]
__global__ __launch_bounds__(NT) void k_wprep(
    const void* mw0,const void* mb0,const void* mw1,const void* mb1,
    const void* mw2,const void* mb2,const void* mw3,const void* mb3,
    const void* We2,const void* ae2,
    const float* __restrict__ stats, float* __restrict__ gw){
  const int f32in=((const int*)stats)[7];
  for(int t=threadIdx.x;t<560;t+=NT) gw[t]=ld(mw0,t,f32in);
  for(int t=threadIdx.x;t<256;t+=NT) gw[576+t]=ld(mw1,t,f32in);
  for(int t=threadIdx.x;t<128;t+=NT) gw[848+t]=ld(mw2,t,f32in);
  if(threadIdx.x<32) gw[984+threadIdx.x]=ld(mw3,threadIdx.x,f32in);
  if(threadIdx.x<16){ gw[560+threadIdx.x]=ld(mb0,threadIdx.x,f32in); gw[832+threadIdx.x]=ld(mb1,threadIdx.x,f32in); }
  if(threadIdx.x<8) gw[976+threadIdx.x]=ld(mb2,threadIdx.x,f32in);
  if(threadIdx.x<4){
    gw[1016+threadIdx.x]=ld(mb3,threadIdx.x,f32in);
    gw[1020+threadIdx.x]=ld(We2,threadIdx.x*2+0,f32in)*ld(ae2,0,f32in)
                        +ld(We2,threadIdx.x*2+1,f32in)*ld(ae2,1,f32in);
  }
}

// MLP eval, i2-OUTER / j-INNER: per input element load one contiguous 64B weight
// row (4x float4, uniform address -> single line request, broadcast to lanes),
// 16 independent FMAs into register accumulators. Per-output accumulation order
// over i2 is unchanged vs reference (bias first, i2 ascending) -> bit-identical.
__device__ __forceinline__ void mlp_eval_g(const float* __restrict__ z,
                                           const float* __restrict__ gw, float* ev){
  const float4* w4=(const float4*)gw;        // mw0: 35 rows x 16 (4 float4/row)
  float t1v[16];
  {
    const float4* b=(const float4*)(gw+560);
    float4 b0=b[0],b1=b[1],b2=b[2],b3=b[3];
    t1v[0]=b0.x; t1v[1]=b0.y; t1v[2]=b0.z; t1v[3]=b0.w;
    t1v[4]=b1.x; t1v[5]=b1.y; t1v[6]=b1.z; t1v[7]=b1.w;
    t1v[8]=b2.x; t1v[9]=b2.y; t1v[10]=b2.z; t1v[11]=b2.w;
    t1v[12]=b3.x; t1v[13]=b3.y; t1v[14]=b3.z; t1v[15]=b3.w;
  }
#pragma unroll
  for(int i2=0;i2<35;i2++){
    float zi=z[i2];
    float4 r0=w4[i2*4+0], r1=w4[i2*4+1], r2=w4[i2*4+2], r3=w4[i2*4+3];
    t1v[0]+=zi*r0.x; t1v[1]+=zi*r0.y; t1v[2]+=zi*r0.z; t1v[3]+=zi*r0.w;
    t1v[4]+=zi*r1.x; t1v[5]+=zi*r1.y; t1v[6]+=zi*r1.z; t1v[7]+=zi*r1.w;
    t1v[8]+=zi*r2.x; t1v[9]+=zi*r2.y; t1v[10]+=zi*r2.z; t1v[11]+=zi*r2.w;
    t1v[12]+=zi*r3.x; t1v[13]+=zi*r3.y; t1v[14]+=zi*r3.z; t1v[15]+=zi*r3.w;
  }
#pragma unroll
  for(int j=0;j<16;j++) t1v[j]=fmaxf(t1v[j],0.f);

  const float4* w14=(const float4*)(gw+576); // mw1: 16 rows x 16
  float t2v[16];
  {
    const float4* b=(const float4*)(gw+832);
    float4 b0=b[0],b1=b[1],b2=b[2],b3=b[3];
    t2v[0]=b0.x; t2v[1]=b0.y; t2v[2]=b0.z; t2v[3]=b0.w;
    t2v[4]=b1.x; t2v[5]=b1.y; t2v[6]=b1.z; t2v[7]=b1.w;
    t2v[8]=b2.x; t2v[9]=b2.y; t2v[10]=b2.z; t2v[11]=b2.w;
    t2v[12]=b3.x; t2v[13]=b3.y; t2v[14]=b3.z; t2v[15]=b3.w;
  }
#pragma unroll
  for(int i2=0;i2<16;i2++){
    float zi=t1v[i2];
    float4 r0=w14[i2*4+0], r1=w14[i2*4+1], r2=w14[i2*4+2], r3=w14[i2*4+3];
    t2v[0]+=zi*r0.x; t2v[1]+=zi*r0.y; t2v[2]+=zi*r0.z; t2v[3]+=zi*r0.w;
    t2v[4]+=zi*r1.x; t2v[5]+=zi*r1.y; t2v[6]+=zi*r1.z; t2v[7]+=zi*r1.w;
    t2v[8]+=zi*r2.x; t2v[9]+=zi*r2.y; t2v[10]+=zi*r2.z; t2v[11]+=zi*r2.w;
    t2v[12]+=zi*r3.x; t2v[13]+=zi*r3.y; t2v[14]+=zi*r3.z; t2v[15]+=zi*r3.w;
  }
#pragma unroll
  for(int j=0;j<16;j++) t2v[j]=fmaxf(t2v[j],0.f);

  const float4* w24=(const float4*)(gw+848); // mw2: 16 rows x 8
  float t3v[8];
  {
    const float4* b=(const float4*)(gw+976);
    float4 b0=b[0],b1=b[1];
    t3v[0]=b0.x; t3v[1]=b0.y; t3v[2]=b0.z; t3v[3]=b0.w;
    t3v[4]=b1.x; t3v[5]=b1.y; t3v[6]=b1.z; t3v[7]=b1.w;
  }
#pragma unroll
  for(int i2=0;i2<16;i2++){
    float zi=t2v[i2];
    float4 r0=w24[i2*2+0], r1=w24[i2*2+1];
    t3v[0]+=zi*r0.x; t3v[1]+=zi*r0.y; t3v[2]+=zi*r0.z; t3v[3]+=zi*r0.w;
    t3v[4]+=zi*r1.x; t3v[5]+=zi*r1.y; t3v[6]+=zi*r1.z; t3v[7]+=zi*r1.w;
  }
#pragma unroll
  for(int j=0;j<8;j++) t3v[j]=fmaxf(t3v[j],0.f);

  const float4* w34=(const float4*)(gw+984); // mw3: 8 rows x 4
  {
    const float4* b=(const float4*)(gw+1016);
    float4 b0=b[0];
    ev[0]=b0.x; ev[1]=b0.y; ev[2]=b0.z; ev[3]=b0.w;
  }
#pragma unroll
  for(int i2=0;i2<8;i2++){
    float zi=t3v[i2];
    float4 r0=w34[i2];
    ev[0]+=zi*r0.x; ev[1]+=zi*r0.y; ev[2]+=zi*r0.z; ev[3]+=zi*r0.w;
  }
}

// ---------------- K6: edge MLP + out1 log_softmax + mean(e) + fused layer-2 softmax accum
__global__ __launch_bounds__(NT) void k_edge2(
    const int* __restrict__ idx, const void* __restrict__ ea,
    const bf16* __restrict__ h1,
    const float* __restrict__ als2, const float* __restrict__ ald2,
    const float* __restrict__ gw,
    const float* __restrict__ h2,
    float* __restrict__ denom2, float* __restrict__ acc2,
    float* __restrict__ stats, void* __restrict__ d_out, int E, int N){
  const int f32in=((const int*)stats)[7];
  __shared__ float s_red[16];
  int e=blockIdx.x*NT+threadIdx.x;
  float e0=0.f,e1=0.f,e2=0.f,e3=0.f;
  if(e<E){
    unsigned s=clampi(idx[e],N), d=clampi(idx[(size_t)E+e],N);
    float z[35];
    load_h1v(h1,s,z);
    z[16]=ld(ea,(size_t)e*3+0,f32in); z[17]=ld(ea,(size_t)e*3+1,f32in); z[18]=ld(ea,(size_t)e*3+2,f32in);
    load_h1v(h1,d,z+19);
    float ev[4];
    mlp_eval_g(z,gw,ev);
    e0=ev[0]; e1=ev[1]; e2=ev[2]; e3=ev[3];
    float m=fmaxf(fmaxf(ev[0],ev[1]),fmaxf(ev[2],ev[3]));
    float lse=m+logf(expf(ev[0]-m)+expf(ev[1]-m)+expf(ev[2]-m)+expf(ev[3]-m));
    if(f32in){
      float4 o; o.x=sanf(ev[0]-lse); o.y=sanf(ev[1]-lse); o.z=sanf(ev[2]-lse); o.w=sanf(ev[3]-lse);
      ((float4*)((float*)d_out+(size_t)2*N))[e]=o;
    }else{
      ull o = (ull)f2bu(sanf(ev[0]-lse))
            | ((ull)f2bu(sanf(ev[1]-lse))<<16)
            | ((ull)f2bu(sanf(ev[2]-lse))<<32)
            | ((ull)f2bu(sanf(ev[3]-lse))<<48);
      ((ull*)((bf16*)d_out+(size_t)2*N))[e]=o;
    }
    const float* s_ve2=gw+1020;
    float adot=ev[0]*s_ve2[0]+ev[1]*s_ve2[1]+ev[2]*s_ve2[2]+ev[3]*s_ve2[3];
    float a2=sanf(lrelu(als2[s]+ald2[d]+adot));
    float ex=expf(fminf(a2,80.f));
    float2 h2s=((const float2*)h2)[s];
    atomicAdd(&denom2[d],ex);
    atomicAdd(&acc2[(size_t)d*2+0],ex*h2s.x);
    atomicAdd(&acc2[(size_t)d*2+1],ex*h2s.y);
  }
  int lane=threadIdx.x&63, wv=threadIdx.x>>6;
  e0=waveReduceSum(e0); e1=waveReduceSum(e1); e2=waveReduceSum(e2); e3=waveReduceSum(e3);
  __syncthreads();
  if(lane==0){ s_red[wv*4]=e0; s_red[wv*4+1]=e1; s_red[wv*4+2]=e2; s_red[wv*4+3]=e3; }
  __syncthreads();
  if(threadIdx.x==0){
    float a0=0,a1=0,a2=0,a3=0;
    for(int w=0;w<NT/64;w++){ a0+=s_red[w*4]; a1+=s_red[w*4+1]; a2+=s_red[w*4+2]; a3+=s_red[w*4+3]; }
    atomicAdd(&stats[3],a0); atomicAdd(&stats[4],a1); atomicAdd(&stats[5],a2); atomicAdd(&stats[6],a3);
  }
}

// ---------------- K7: fused self-loop fold + layer-2 epilogue + out0 log_softmax
__global__ __launch_bounds__(NT) void k_final(
    const float* __restrict__ stats, float invE,
    const float* __restrict__ als2, const float* __restrict__ ald2,
    const void* __restrict__ We2, const void* __restrict__ ae2,
    const float* __restrict__ h2,
    const float* __restrict__ denom2, const float* __restrict__ acc2,
    const void* __restrict__ bias2, void* __restrict__ d_out, int N){
  const int f32in=((const int*)stats)[7];
  __shared__ float s_ve2[4], s_b2[2];
  if(threadIdx.x<4)
    s_ve2[threadIdx.x]=ld(We2,threadIdx.x*2+0,f32in)*ld(ae2,0,f32in)
                      +ld(We2,threadIdx.x*2+1,f32in)*ld(ae2,1,f32in);
  if(threadIdx.x<2) s_b2[threadIdx.x]=ld(bias2,threadIdx.x,f32in);
  __syncthreads();
  int i=blockIdx.x*NT+threadIdx.x;
  if(i>=N) return;
  float adot=(stats[3]*s_ve2[0]+stats[4]*s_ve2[1]+stats[5]*s_ve2[2]+stats[6]*s_ve2[3])*invE;
  float self=lrelu(als2[i]+ald2[i]+adot);
  float ex=expf(fminf(self,80.f));
  float den=denom2[i]+ex;
  float inv=1.f/(den+1e-16f);
  float o0=(acc2[(size_t)i*2+0]+ex*h2[(size_t)i*2+0])*inv+s_b2[0];
  float o1=(acc2[(size_t)i*2+1]+ex*h2[(size_t)i*2+1])*inv+s_b2[1];
  float m=fmaxf(o0,o1);
  float lse=m+logf(expf(o0-m)+expf(o1-m));
  float r0=sanf(o0-lse), r1=sanf(o1-lse);
  if(f32in){
    float* o=(float*)d_out;
    o[(size_t)i*2+0]=r0; o[(size_t)i*2+1]=r1;
  }else{
    bf16* o=(bf16*)d_out;
    o[(size_t)i*2+0]=f2b(r0); o[(size_t)i*2+1]=f2b(r1);
  }
}

extern "C" void kernel_launch(void* const* d_in, const int* in_sizes, int n_in,
                              void* d_out, int out_size, void* d_ws, size_t ws_size,
                              hipStream_t stream){
  const void* x   =d_in[0];
  const void* ea  =d_in[1];
  const void* W1  =d_in[2];
  const void* as1 =d_in[3];
  const void* ad1 =d_in[4];
  const void* We1 =d_in[5];
  const void* ae1 =d_in[6];
  const void* b1  =d_in[7];
  const void* mw0 =d_in[8];
  const void* mb0 =d_in[9];
  const void* mw1 =d_in[10];
  const void* mb1 =d_in[11];
  const void* mw2 =d_in[12];
  const void* mb2 =d_in[13];
  const void* mw3 =d_in[14];
  const void* mb3 =d_in[15];
  const void* W2  =d_in[16];
  const void* as2 =d_in[17];
  const void* ad2 =d_in[18];
  const void* We2 =d_in[19];
  const void* ae2 =d_in[20];
  const void* bias2=d_in[21];
  const int*  idx =(const int*)d_in[22];

  int N=in_sizes[0]/4;
  int E=in_sizes[1]/3;
  float invE=1.f/(float)E;

  float*    F     =(float*)d_ws;
  float*    stats =F;                         // 8
  float*    als   =F+8;                       // N   (als2 aliases after gather1)
  float*    ald   =als+N;                     // N   (den2 aliases after gather1)
  float*    ald2  =ald+N;                     // N
  int*      rowc  =(int*)(ald2+N);            // N   (hist -> start -> end; dead after gather1, then gw)
  bf16*     h1    =(bf16*)(rowc+N);           // 16N bf16 = 8N floats
  float*    h2    =(float*)(h1+(size_t)16*N); // 2N
  float*    acc2  =h2+(size_t)2*N;            // 2N
  float*    den2  =ald;
  // gw: 1040 f32 in the dead rowc region, 16B-aligned for float4 loads
  float*    gw    =(float*)((((uintptr_t)rowc)+15)&~(uintptr_t)15);

  ull* csr =(ull*)((char*)d_out+(size_t)4*N);
  int* bsum=(int*)((char*)d_out+(size_t)4*N);

  int NBn=(N+NT-1)/NT, nbE=(E+NT-1)/NT;
  int nscan=in_sizes[0]*2; if(nscan>512) nscan=512;

  hipMemsetAsync(rowc,0,(size_t)N*sizeof(int),stream);
  k_probe  <<<1,64,0,stream>>>((const unsigned short*)x,nscan,stats);
  k_prep   <<<1024,NT,0,stream>>>(ea,idx,rowc,stats,E,N);
  k_node1  <<<NBn,NT,0,stream>>>(x,W1,as1,ad1,stats,als,ald,N);
  k_scan1  <<<NBn,NT,0,stream>>>(rowc,bsum,N);
  k_scan2  <<<1,1024,0,stream>>>(bsum,NBn);
  k_scan3  <<<NBn,NT,0,stream>>>(rowc,bsum,N);
  k_scatter<<<nbE,NT,0,stream>>>(idx,ea,We1,ae1,als,stats,rowc,csr,E,N);
  k_gather1<<<(N+15)/16,NT,0,stream>>>(csr,rowc,als,ald,x,W1,b1,W2,as2,ad2,We1,ae1,
                                       stats,invE,h1,h2,als,ald2,N);
  k_wprep  <<<1,NT,0,stream>>>(mw0,mb0,mw1,mb1,mw2,mb2,mw3,mb3,We2,ae2,stats,gw);
  hipMemsetAsync(den2,0,(size_t)N*sizeof(float),stream);
  hipMemsetAsync(acc2,0,(size_t)2*N*sizeof(float),stream);
  k_edge2  <<<nbE,NT,0,stream>>>(idx,ea,h1,als,ald2,gw,h2,den2,acc2,stats,d_out,E,N);
  k_final  <<<NBn,NT,0,stream>>>(stats,invE,als,ald2,We2,ae2,h2,den2,acc2,bias2,d_out,N);
}

// Round 4
// 1213.545 us; speedup vs baseline: 1.2227x; 1.2227x over previous
//
#include <hip/hip_runtime.h>
#include <hip/hip_bf16.h>
#include <stdint.h>

typedef __hip_bfloat16 bf16;
typedef unsigned long long ull;
#define NT 256

__device__ __forceinline__ float b2f(bf16 v){ return __bfloat162float(v); }
__device__ __forceinline__ bf16 f2b(float v){ return __float2bfloat16(v); }
__device__ __forceinline__ float lrelu(float a){ return a>0.f ? a : 0.2f*a; }
__device__ __forceinline__ float sanf(float v){ return __builtin_isfinite(v) ? v : -12345.f; }
__device__ __forceinline__ float us2f(unsigned short u){ return __uint_as_float(((unsigned)u)<<16); }
__device__ __forceinline__ unsigned short f2bu(float v){ bf16 b=f2b(v); unsigned short u; __builtin_memcpy(&u,&b,2); return u; }

// dtype-flexible input load: f32in ? float : bf16
__device__ __forceinline__ float ld(const void* p, size_t i, int f32in){
  return f32in ? ((const float*)p)[i] : b2f(((const bf16*)p)[i]);
}

__device__ __forceinline__ float waveReduceSum(float v){
#pragma unroll
  for(int o=32;o>0;o>>=1) v += __shfl_down(v,o,64);
  return v;
}

__device__ __forceinline__ unsigned clampi(int v, int n){
  unsigned u=(unsigned)v; return (u<(unsigned)n)?u:0u;
}

// vectorized bf16 h1 row load (16 ch = 4x 8B)
__device__ __forceinline__ void load_h1v(const bf16* h1, unsigned node, float* dst){
  const ull* p=(const ull*)(h1+(size_t)node*16);
#pragma unroll
  for(int q=0;q<4;q++){
    ull v=p[q];
    dst[q*4+0]=us2f((unsigned short)v);        dst[q*4+1]=us2f((unsigned short)(v>>16));
    dst[q*4+2]=us2f((unsigned short)(v>>32));  dst[q*4+3]=us2f((unsigned short)(v>>48));
  }
}
// x row (4 ch) load, dtype-flex
__device__ __forceinline__ void load_x4(const void* x, unsigned n, int f32in, float* o){
  if(f32in){ float4 v=((const float4*)x)[n]; o[0]=v.x;o[1]=v.y;o[2]=v.z;o[3]=v.w; }
  else{
    ull v=((const ull*)x)[n];
    o[0]=us2f((unsigned short)v);       o[1]=us2f((unsigned short)(v>>16));
    o[2]=us2f((unsigned short)(v>>32)); o[3]=us2f((unsigned short)(v>>48));
  }
}

// ---------------- K0: zero stats, detect input dtype -> ((int*)stats)[7]
__global__ __launch_bounds__(64) void k_probe(const unsigned short* __restrict__ xraw,
                                              int nscan, float* __restrict__ stats){
  int t=threadIdx.x;
  int bad=0;
  for(int k=t*8;k<t*8+8;k++){
    if(k<nscan){
      unsigned short u=xraw[k];
      unsigned ex=(u>>7)&0xFF;
      bool plaus = (ex==0u) || (ex>=97u && ex<=157u);
      if(!plaus) bad++;
    }
  }
#pragma unroll
  for(int o=32;o>0;o>>=1) bad += __shfl_down(bad,o,64);
  if(t==0){
    for(int i=0;i<7;i++) stats[i]=0.f;
    ((int*)stats)[7] = (bad>=8) ? 1 : 0;
  }
}

// ---------------- K1: histogram of destinations + edge_attr sums -> stats[0..2]
__global__ __launch_bounds__(NT) void k_prep(const void* __restrict__ ea,
                                             const int* __restrict__ idx,
                                             int* __restrict__ rowc,
                                             float* __restrict__ stats, int E, int N){
  const int f32in=((const int*)stats)[7];
  __shared__ float lds[16];
  float s0=0.f,s1=0.f,s2=0.f;
  for(size_t e=(size_t)blockIdx.x*NT+threadIdx.x; e<(size_t)E; e+=(size_t)gridDim.x*NT){
    s0+=ld(ea,e*3+0,f32in); s1+=ld(ea,e*3+1,f32in); s2+=ld(ea,e*3+2,f32in);
    unsigned d=clampi(idx[(size_t)E+e],N);
    atomicAdd(&rowc[d],1);
  }
  int lane=threadIdx.x&63, wv=threadIdx.x>>6;
  s0=waveReduceSum(s0); s1=waveReduceSum(s1); s2=waveReduceSum(s2);
  if(lane==0){ lds[wv*4+0]=s0; lds[wv*4+1]=s1; lds[wv*4+2]=s2; }
  __syncthreads();
  if(threadIdx.x==0){
    float a0=0,a1=0,a2=0;
    for(int w=0;w<NT/64;w++){ a0+=lds[w*4]; a1+=lds[w*4+1]; a2+=lds[w*4+2]; }
    atomicAdd(&stats[0],a0); atomicAdd(&stats[1],a1); atomicAdd(&stats[2],a2);
  }
}

// ---------------- K2: als/ald per node
__global__ __launch_bounds__(NT) void k_node1(
    const void* __restrict__ x, const void* __restrict__ W1,
    const void* __restrict__ as1, const void* __restrict__ ad1,
    const float* __restrict__ stats,
    float* __restrict__ als, float* __restrict__ ald, int N){
  const int f32in=((const int*)stats)[7];
  __shared__ float sW1[64], sas[16], sad[16];
  if(threadIdx.x<64) sW1[threadIdx.x]=ld(W1,threadIdx.x,f32in);
  if(threadIdx.x<16){ sas[threadIdx.x]=ld(as1,threadIdx.x,f32in); sad[threadIdx.x]=ld(ad1,threadIdx.x,f32in); }
  __syncthreads();
  int i=blockIdx.x*NT+threadIdx.x;
  if(i>=N) return;
  float xv[4]; load_x4(x,(unsigned)i,f32in,xv);
  float a_s=0.f,a_d=0.f;
#pragma unroll
  for(int j=0;j<16;j++){
    float v=xv[0]*sW1[j]+xv[1]*sW1[16+j]+xv[2]*sW1[32+j]+xv[3]*sW1[48+j];
    a_s+=v*sas[j]; a_d+=v*sad[j];
  }
  als[i]=a_s; ald[i]=a_d;
}

// ---------------- scan (3 kernels): rowc hist -> exclusive starts
__global__ __launch_bounds__(NT) void k_scan1(const int* __restrict__ rowc, int* __restrict__ bsum, int N){
  __shared__ int sm[NT];
  int i=blockIdx.x*NT+threadIdx.x;
  sm[threadIdx.x]=(i<N)?rowc[i]:0;
  __syncthreads();
  for(int o=NT/2;o>0;o>>=1){ if(threadIdx.x<o) sm[threadIdx.x]+=sm[threadIdx.x+o]; __syncthreads(); }
  if(threadIdx.x==0) bsum[blockIdx.x]=sm[0];
}
__global__ __launch_bounds__(1024) void k_scan2(int* __restrict__ bsum, int NB){
  __shared__ int sm[1024];
  int i=threadIdx.x;
  int v=(i<NB)?bsum[i]:0;
  sm[i]=v; __syncthreads();
  for(int o=1;o<1024;o<<=1){
    int t=(i>=o)?sm[i-o]:0; __syncthreads();
    sm[i]+=t; __syncthreads();
  }
  if(i<NB) bsum[i]=(i==0)?0:sm[i-1];
}
__global__ __launch_bounds__(NT) void k_scan3(int* __restrict__ rowc, const int* __restrict__ bsum, int N){
  __shared__ int sm[NT];
  int i=blockIdx.x*NT+threadIdx.x;
  int v=(i<N)?rowc[i]:0;
  sm[threadIdx.x]=v; __syncthreads();
  for(int o=1;o<NT;o<<=1){
    int t=(threadIdx.x>=o)?sm[threadIdx.x-o]:0; __syncthreads();
    sm[threadIdx.x]+=t; __syncthreads();
  }
  if(i<N) rowc[i]=bsum[blockIdx.x]+sm[threadIdx.x]-v;   // exclusive start
}

// ---------------- K3: scatter packed {src, alpha_partial} into CSR slots; rowc -> end
__global__ __launch_bounds__(NT) void k_scatter(
    const int* __restrict__ idx, const void* __restrict__ ea,
    const void* __restrict__ We1, const void* __restrict__ ae1,
    const float* __restrict__ als, const float* __restrict__ stats,
    int* __restrict__ rowc, ull* __restrict__ csr, int E, int N){
  const int f32in=((const int*)stats)[7];
  __shared__ float sve[3];
  if(threadIdx.x<3){
    float v=0.f;
    for(int j=0;j<16;j++) v+=ld(We1,threadIdx.x*16+j,f32in)*ld(ae1,j,f32in);
    sve[threadIdx.x]=v;
  }
  __syncthreads();
  int e=blockIdx.x*NT+threadIdx.x;
  if(e>=E) return;
  unsigned s=clampi(idx[e],N), d=clampi(idx[(size_t)E+e],N);
  float ap = als[s] + ld(ea,(size_t)e*3+0,f32in)*sve[0]
                    + ld(ea,(size_t)e*3+1,f32in)*sve[1]
                    + ld(ea,(size_t)e*3+2,f32in)*sve[2];
  int pos=atomicAdd(&rowc[d],1);
  csr[pos] = (ull)s | ((ull)__float_as_uint(ap)<<32);
}

// ---------------- K4: gather-aggregate layer-1 softmax; write h1(bf16), h2, als2, ald2
// 16 lanes per node; 4 nodes per wave; 16 nodes per block.
__global__ __launch_bounds__(NT) void k_gather1(
    const ull* __restrict__ csr, const int* __restrict__ rowe,
    const float* __restrict__ als, const float* __restrict__ ald,
    const void* __restrict__ x, const void* __restrict__ W1, const void* __restrict__ b1,
    const void* __restrict__ W2, const void* __restrict__ as2, const void* __restrict__ ad2,
    const void* __restrict__ We1, const void* __restrict__ ae1,
    const float* __restrict__ stats, float invE,
    bf16* __restrict__ h1, float* __restrict__ h2,
    float* __restrict__ als2, float* __restrict__ ald2, int N){
  const int f32in=((const int*)stats)[7];
  __shared__ float sW1[64], sb1[16], sW2[32], sas2[2], sad2[2], saea[1];
  if(threadIdx.x<64) sW1[threadIdx.x]=ld(W1,threadIdx.x,f32in);
  if(threadIdx.x<16) sb1[threadIdx.x]=ld(b1,threadIdx.x,f32in);
  if(threadIdx.x<32) sW2[threadIdx.x]=ld(W2,threadIdx.x,f32in);
  if(threadIdx.x<2){ sas2[threadIdx.x]=ld(as2,threadIdx.x,f32in); sad2[threadIdx.x]=ld(ad2,threadIdx.x,f32in); }
  if(threadIdx.x==0){
    float a=0.f;
    for(int k=0;k<3;k++){
      float v=0.f;
      for(int j=0;j<16;j++) v+=ld(We1,k*16+j,f32in)*ld(ae1,j,f32in);
      a+=stats[k]*v;
    }
    saea[0]=a*invE;
  }
  __syncthreads();
  int n=blockIdx.x*16+(threadIdx.x>>4);
  int c=threadIdx.x&15;
  if(n>=N) return;
  int end=rowe[n];
  int start=(n==0)?0:rowe[n-1];
  float aldn=ald[n], alsn=als[n];
  float aself=lrelu(alsn+aldn+saea[0]);
  float w0=sW1[c], w1=sW1[16+c], w2=sW1[32+c], w3=sW1[48+c];
  // phase A: segment max (strided over slots)
  float m=aself;
  for(int k=start+c;k<end;k+=16){
    float ap=__uint_as_float((unsigned)(csr[k]>>32));
    m=fmaxf(m,lrelu(ap+aldn));
  }
#pragma unroll
  for(int o=1;o<16;o<<=1) m=fmaxf(m,__shfl_xor(m,o,64));
  // self contribution
  float xv[4]; load_x4(x,(unsigned)n,f32in,xv);
  float hc_self=xv[0]*w0+xv[1]*w1+xv[2]*w2+xv[3]*w3;
  float exs=expf(fminf(aself-m,0.f));
  float den=exs, acc=exs*hc_self;
  // phase B: serial over slots, lane c = channel
  for(int k=start;k<end;k++){
    ull v=csr[k];
    unsigned src=(unsigned)(v&0xffffffffu);
    float ap=__uint_as_float((unsigned)(v>>32));
    float ex=expf(fminf(lrelu(ap+aldn)-m,0.f));
    den+=ex;
    float xs[4]; load_x4(x,src,f32in,xs);
    float hc=xs[0]*w0+xs[1]*w1+xs[2]*w2+xs[3]*w3;
    acc+=ex*hc;
  }
  float inv=1.f/(den+1e-16f);
  float h1c=acc*inv+sb1[c];
  h1[(size_t)n*16+c]=f2b(h1c);
  float r0=h1c*sW2[c*2+0], r1=h1c*sW2[c*2+1];
#pragma unroll
  for(int o=1;o<16;o<<=1){ r0+=__shfl_xor(r0,o,64); r1+=__shfl_xor(r1,o,64); }
  if(c==0){
    h2[(size_t)n*2+0]=r0; h2[(size_t)n*2+1]=r1;
    als2[n]=r0*sas2[0]+r1*sas2[1];
    ald2[n]=r0*sad2[0]+r1*sad2[1];
  }
}

// ---------------- K5: normalize all edge-MLP weights to f32 in global gw[1040]
__global__ __launch_bounds__(NT) void k_wprep(
    const void* mw0,const void* mb0,const void* mw1,const void* mb1,
    const void* mw2,const void* mb2,const void* mw3,const void* mb3,
    const void* We2,const void* ae2,
    const float* __restrict__ stats, float* __restrict__ gw){
  const int f32in=((const int*)stats)[7];
  for(int t=threadIdx.x;t<560;t+=NT) gw[t]=ld(mw0,t,f32in);
  for(int t=threadIdx.x;t<256;t+=NT) gw[576+t]=ld(mw1,t,f32in);
  for(int t=threadIdx.x;t<128;t+=NT) gw[848+t]=ld(mw2,t,f32in);
  if(threadIdx.x<32) gw[984+threadIdx.x]=ld(mw3,threadIdx.x,f32in);
  if(threadIdx.x<16){ gw[560+threadIdx.x]=ld(mb0,threadIdx.x,f32in); gw[832+threadIdx.x]=ld(mb1,threadIdx.x,f32in); }
  if(threadIdx.x<8) gw[976+threadIdx.x]=ld(mb2,threadIdx.x,f32in);
  if(threadIdx.x<4){
    gw[1016+threadIdx.x]=ld(mb3,threadIdx.x,f32in);
    gw[1020+threadIdx.x]=ld(We2,threadIdx.x*2+0,f32in)*ld(ae2,0,f32in)
                        +ld(We2,threadIdx.x*2+1,f32in)*ld(ae2,1,f32in);
  }
}

// Dual-edge MLP eval: one weight-row load feeds TWO independent edges' FMAs.
// Per-output accumulation order over i2 unchanged per edge -> bit-identical.
__device__ __forceinline__ void mlp_eval_g2(const float* __restrict__ zA,
                                            const float* __restrict__ zB,
                                            const float* __restrict__ gw,
                                            float* evA, float* evB){
  const float4* w4=(const float4*)gw;        // mw0: 35 rows x 16
  float tA[16], tB[16];
  {
    const float4* b=(const float4*)(gw+560);
    float4 b0=b[0],b1=b[1],b2=b[2],b3=b[3];
    tA[0]=b0.x; tA[1]=b0.y; tA[2]=b0.z; tA[3]=b0.w;
    tA[4]=b1.x; tA[5]=b1.y; tA[6]=b1.z; tA[7]=b1.w;
    tA[8]=b2.x; tA[9]=b2.y; tA[10]=b2.z; tA[11]=b2.w;
    tA[12]=b3.x; tA[13]=b3.y; tA[14]=b3.z; tA[15]=b3.w;
#pragma unroll
    for(int j=0;j<16;j++) tB[j]=tA[j];
  }
#pragma unroll
  for(int i2=0;i2<35;i2++){
    float a=zA[i2], b=zB[i2];
    float4 r0=w4[i2*4+0], r1=w4[i2*4+1], r2=w4[i2*4+2], r3=w4[i2*4+3];
    tA[0]+=a*r0.x; tA[1]+=a*r0.y; tA[2]+=a*r0.z; tA[3]+=a*r0.w;
    tB[0]+=b*r0.x; tB[1]+=b*r0.y; tB[2]+=b*r0.z; tB[3]+=b*r0.w;
    tA[4]+=a*r1.x; tA[5]+=a*r1.y; tA[6]+=a*r1.z; tA[7]+=a*r1.w;
    tB[4]+=b*r1.x; tB[5]+=b*r1.y; tB[6]+=b*r1.z; tB[7]+=b*r1.w;
    tA[8]+=a*r2.x; tA[9]+=a*r2.y; tA[10]+=a*r2.z; tA[11]+=a*r2.w;
    tB[8]+=b*r2.x; tB[9]+=b*r2.y; tB[10]+=b*r2.z; tB[11]+=b*r2.w;
    tA[12]+=a*r3.x; tA[13]+=a*r3.y; tA[14]+=a*r3.z; tA[15]+=a*r3.w;
    tB[12]+=b*r3.x; tB[13]+=b*r3.y; tB[14]+=b*r3.z; tB[15]+=b*r3.w;
  }
#pragma unroll
  for(int j=0;j<16;j++){ tA[j]=fmaxf(tA[j],0.f); tB[j]=fmaxf(tB[j],0.f); }

  const float4* w14=(const float4*)(gw+576); // mw1: 16 rows x 16
  float uA[16], uB[16];
  {
    const float4* b=(const float4*)(gw+832);
    float4 b0=b[0],b1=b[1],b2=b[2],b3=b[3];
    uA[0]=b0.x; uA[1]=b0.y; uA[2]=b0.z; uA[3]=b0.w;
    uA[4]=b1.x; uA[5]=b1.y; uA[6]=b1.z; uA[7]=b1.w;
    uA[8]=b2.x; uA[9]=b2.y; uA[10]=b2.z; uA[11]=b2.w;
    uA[12]=b3.x; uA[13]=b3.y; uA[14]=b3.z; uA[15]=b3.w;
#pragma unroll
    for(int j=0;j<16;j++) uB[j]=uA[j];
  }
#pragma unroll
  for(int i2=0;i2<16;i2++){
    float a=tA[i2], b=tB[i2];
    float4 r0=w14[i2*4+0], r1=w14[i2*4+1], r2=w14[i2*4+2], r3=w14[i2*4+3];
    uA[0]+=a*r0.x; uA[1]+=a*r0.y; uA[2]+=a*r0.z; uA[3]+=a*r0.w;
    uB[0]+=b*r0.x; uB[1]+=b*r0.y; uB[2]+=b*r0.z; uB[3]+=b*r0.w;
    uA[4]+=a*r1.x; uA[5]+=a*r1.y; uA[6]+=a*r1.z; uA[7]+=a*r1.w;
    uB[4]+=b*r1.x; uB[5]+=b*r1.y; uB[6]+=b*r1.z; uB[7]+=b*r1.w;
    uA[8]+=a*r2.x; uA[9]+=a*r2.y; uA[10]+=a*r2.z; uA[11]+=a*r2.w;
    uB[8]+=b*r2.x; uB[9]+=b*r2.y; uB[10]+=b*r2.z; uB[11]+=b*r2.w;
    uA[12]+=a*r3.x; uA[13]+=a*r3.y; uA[14]+=a*r3.z; uA[15]+=a*r3.w;
    uB[12]+=b*r3.x; uB[13]+=b*r3.y; uB[14]+=b*r3.z; uB[15]+=b*r3.w;
  }
#pragma unroll
  for(int j=0;j<16;j++){ uA[j]=fmaxf(uA[j],0.f); uB[j]=fmaxf(uB[j],0.f); }

  const float4* w24=(const float4*)(gw+848); // mw2: 16 rows x 8
  float vA[8], vB[8];
  {
    const float4* b=(const float4*)(gw+976);
    float4 b0=b[0],b1=b[1];
    vA[0]=b0.x; vA[1]=b0.y; vA[2]=b0.z; vA[3]=b0.w;
    vA[4]=b1.x; vA[5]=b1.y; vA[6]=b1.z; vA[7]=b1.w;
#pragma unroll
    for(int j=0;j<8;j++) vB[j]=vA[j];
  }
#pragma unroll
  for(int i2=0;i2<16;i2++){
    float a=uA[i2], b=uB[i2];
    float4 r0=w24[i2*2+0], r1=w24[i2*2+1];
    vA[0]+=a*r0.x; vA[1]+=a*r0.y; vA[2]+=a*r0.z; vA[3]+=a*r0.w;
    vB[0]+=b*r0.x; vB[1]+=b*r0.y; vB[2]+=b*r0.z; vB[3]+=b*r0.w;
    vA[4]+=a*r1.x; vA[5]+=a*r1.y; vA[6]+=a*r1.z; vA[7]+=a*r1.w;
    vB[4]+=b*r1.x; vB[5]+=b*r1.y; vB[6]+=b*r1.z; vB[7]+=b*r1.w;
  }
#pragma unroll
  for(int j=0;j<8;j++){ vA[j]=fmaxf(vA[j],0.f); vB[j]=fmaxf(vB[j],0.f); }

  const float4* w34=(const float4*)(gw+984); // mw3: 8 rows x 4
  {
    const float4* b=(const float4*)(gw+1016);
    float4 b0=b[0];
    evA[0]=b0.x; evA[1]=b0.y; evA[2]=b0.z; evA[3]=b0.w;
    evB[0]=b0.x; evB[1]=b0.y; evB[2]=b0.z; evB[3]=b0.w;
  }
#pragma unroll
  for(int i2=0;i2<8;i2++){
    float a=vA[i2], b=vB[i2];
    float4 r0=w34[i2];
    evA[0]+=a*r0.x; evA[1]+=a*r0.y; evA[2]+=a*r0.z; evA[3]+=a*r0.w;
    evB[0]+=b*r0.x; evB[1]+=b*r0.y; evB[2]+=b*r0.z; evB[3]+=b*r0.w;
  }
}

// per-edge epilogue: out1 log_softmax store + layer-2 alpha accum
__device__ __forceinline__ void edge_epi(const float* ev, unsigned s, unsigned d, int e,
                                         const float* __restrict__ gw,
                                         const float* __restrict__ als2,
                                         const float* __restrict__ ald2,
                                         const float* __restrict__ h2,
                                         float* __restrict__ denom2, float* __restrict__ acc2,
                                         void* __restrict__ d_out, int f32in, int N){
  float m=fmaxf(fmaxf(ev[0],ev[1]),fmaxf(ev[2],ev[3]));
  float lse=m+logf(expf(ev[0]-m)+expf(ev[1]-m)+expf(ev[2]-m)+expf(ev[3]-m));
  if(f32in){
    float4 o; o.x=sanf(ev[0]-lse); o.y=sanf(ev[1]-lse); o.z=sanf(ev[2]-lse); o.w=sanf(ev[3]-lse);
    ((float4*)((float*)d_out+(size_t)2*N))[e]=o;
  }else{
    ull o = (ull)f2bu(sanf(ev[0]-lse))
          | ((ull)f2bu(sanf(ev[1]-lse))<<16)
          | ((ull)f2bu(sanf(ev[2]-lse))<<32)
          | ((ull)f2bu(sanf(ev[3]-lse))<<48);
    ((ull*)((bf16*)d_out+(size_t)2*N))[e]=o;
  }
  const float* s_ve2=gw+1020;
  float adot=ev[0]*s_ve2[0]+ev[1]*s_ve2[1]+ev[2]*s_ve2[2]+ev[3]*s_ve2[3];
  float a2=sanf(lrelu(als2[s]+ald2[d]+adot));
  float ex=expf(fminf(a2,80.f));
  float2 h2s=((const float2*)h2)[s];
  atomicAdd(&denom2[d],ex);
  atomicAdd(&acc2[(size_t)d*2+0],ex*h2s.x);
  atomicAdd(&acc2[(size_t)d*2+1],ex*h2s.y);
}

// ---------------- K6: edge MLP (2 edges/thread) + out1 + mean(e) + fused layer-2 accum
__global__ __launch_bounds__(NT) void k_edge2(
    const int* __restrict__ idx, const void* __restrict__ ea,
    const bf16* __restrict__ h1,
    const float* __restrict__ als2, const float* __restrict__ ald2,
    const float* __restrict__ gw,
    const float* __restrict__ h2,
    float* __restrict__ denom2, float* __restrict__ acc2,
    float* __restrict__ stats, void* __restrict__ d_out, int E, int N){
  const int f32in=((const int*)stats)[7];
  __shared__ float s_red[16];
  size_t base=(size_t)blockIdx.x*(NT*2)+threadIdx.x;
  int eA=(int)base, eB=(int)(base+NT);
  bool vA=eA<E, vB=eB<E;
  int eAs=vA?eA:0, eBs=vB?eB:0;
  unsigned sA=clampi(idx[eAs],N), dA=clampi(idx[(size_t)E+eAs],N);
  unsigned sB=clampi(idx[eBs],N), dB=clampi(idx[(size_t)E+eBs],N);
  float zA[35], zB[35];
  load_h1v(h1,sA,zA); load_h1v(h1,dA,zA+19);
  load_h1v(h1,sB,zB); load_h1v(h1,dB,zB+19);
  zA[16]=ld(ea,(size_t)eAs*3+0,f32in); zA[17]=ld(ea,(size_t)eAs*3+1,f32in); zA[18]=ld(ea,(size_t)eAs*3+2,f32in);
  zB[16]=ld(ea,(size_t)eBs*3+0,f32in); zB[17]=ld(ea,(size_t)eBs*3+1,f32in); zB[18]=ld(ea,(size_t)eBs*3+2,f32in);
  float evA[4], evB[4];
  mlp_eval_g2(zA,zB,gw,evA,evB);
  float c0=0.f,c1=0.f,c2=0.f,c3=0.f;
  if(vA){
    edge_epi(evA,sA,dA,eA,gw,als2,ald2,h2,denom2,acc2,d_out,f32in,N);
    c0+=evA[0]; c1+=evA[1]; c2+=evA[2]; c3+=evA[3];
  }
  if(vB){
    edge_epi(evB,sB,dB,eB,gw,als2,ald2,h2,denom2,acc2,d_out,f32in,N);
    c0+=evB[0]; c1+=evB[1]; c2+=evB[2]; c3+=evB[3];
  }
  int lane=threadIdx.x&63, wv=threadIdx.x>>6;
  c0=waveReduceSum(c0); c1=waveReduceSum(c1); c2=waveReduceSum(c2); c3=waveReduceSum(c3);
  __syncthreads();
  if(lane==0){ s_red[wv*4]=c0; s_red[wv*4+1]=c1; s_red[wv*4+2]=c2; s_red[wv*4+3]=c3; }
  __syncthreads();
  if(threadIdx.x==0){
    float a0=0,a1=0,a2=0,a3=0;
    for(int w=0;w<NT/64;w++){ a0+=s_red[w*4]; a1+=s_red[w*4+1]; a2+=s_red[w*4+2]; a3+=s_red[w*4+3]; }
    atomicAdd(&stats[3],a0); atomicAdd(&stats[4],a1); atomicAdd(&stats[5],a2); atomicAdd(&stats[6],a3);
  }
}

// ---------------- K7: fused self-loop fold + layer-2 epilogue + out0 log_softmax
__global__ __launch_bounds__(NT) void k_final(
    const float* __restrict__ stats, float invE,
    const float* __restrict__ als2, const float* __restrict__ ald2,
    const void* __restrict__ We2, const void* __restrict__ ae2,
    const float* __restrict__ h2,
    const float* __restrict__ denom2, const float* __restrict__ acc2,
    const void* __restrict__ bias2, void* __restrict__ d_out, int N){
  const int f32in=((const int*)stats)[7];
  __shared__ float s_ve2[4], s_b2[2];
  if(threadIdx.x<4)
    s_ve2[threadIdx.x]=ld(We2,threadIdx.x*2+0,f32in)*ld(ae2,0,f32in)
                      +ld(We2,threadIdx.x*2+1,f32in)*ld(ae2,1,f32in);
  if(threadIdx.x<2) s_b2[threadIdx.x]=ld(bias2,threadIdx.x,f32in);
  __syncthreads();
  int i=blockIdx.x*NT+threadIdx.x;
  if(i>=N) return;
  float adot=(stats[3]*s_ve2[0]+stats[4]*s_ve2[1]+stats[5]*s_ve2[2]+stats[6]*s_ve2[3])*invE;
  float self=lrelu(als2[i]+ald2[i]+adot);
  float ex=expf(fminf(self,80.f));
  float den=denom2[i]+ex;
  float inv=1.f/(den+1e-16f);
  float o0=(acc2[(size_t)i*2+0]+ex*h2[(size_t)i*2+0])*inv+s_b2[0];
  float o1=(acc2[(size_t)i*2+1]+ex*h2[(size_t)i*2+1])*inv+s_b2[1];
  float m=fmaxf(o0,o1);
  float lse=m+logf(expf(o0-m)+expf(o1-m));
  float r0=sanf(o0-lse), r1=sanf(o1-lse);
  if(f32in){
    float* o=(float*)d_out;
    o[(size_t)i*2+0]=r0; o[(size_t)i*2+1]=r1;
  }else{
    bf16* o=(bf16*)d_out;
    o[(size_t)i*2+0]=f2b(r0); o[(size_t)i*2+1]=f2b(r1);
  }
}

extern "C" void kernel_launch(void* const* d_in, const int* in_sizes, int n_in,
                              void* d_out, int out_size, void* d_ws, size_t ws_size,
                              hipStream_t stream){
  const void* x   =d_in[0];
  const void* ea  =d_in[1];
  const void* W1  =d_in[2];
  const void* as1 =d_in[3];
  const void* ad1 =d_in[4];
  const void* We1 =d_in[5];
  const void* ae1 =d_in[6];
  const void* b1  =d_in[7];
  const void* mw0 =d_in[8];
  const void* mb0 =d_in[9];
  const void* mw1 =d_in[10];
  const void* mb1 =d_in[11];
  const void* mw2 =d_in[12];
  const void* mb2 =d_in[13];
  const void* mw3 =d_in[14];
  const void* mb3 =d_in[15];
  const void* W2  =d_in[16];
  const void* as2 =d_in[17];
  const void* ad2 =d_in[18];
  const void* We2 =d_in[19];
  const void* ae2 =d_in[20];
  const void* bias2=d_in[21];
  const int*  idx =(const int*)d_in[22];

  int N=in_sizes[0]/4;
  int E=in_sizes[1]/3;
  float invE=1.f/(float)E;

  float*    F     =(float*)d_ws;
  float*    stats =F;                         // 8
  float*    als   =F+8;                       // N   (als2 aliases after gather1)
  float*    ald   =als+N;                     // N   (den2 aliases after gather1)
  float*    ald2  =ald+N;                     // N
  int*      rowc  =(int*)(ald2+N);            // N   (hist -> start -> end; dead after gather1, then gw)
  bf16*     h1    =(bf16*)(rowc+N);           // 16N bf16 = 8N floats
  float*    h2    =(float*)(h1+(size_t)16*N); // 2N
  float*    acc2  =h2+(size_t)2*N;            // 2N
  float*    den2  =ald;
  // gw: 1040 f32 in the dead rowc region, 16B-aligned for float4 loads
  float*    gw    =(float*)((((uintptr_t)rowc)+15)&~(uintptr_t)15);

  ull* csr =(ull*)((char*)d_out+(size_t)4*N);
  int* bsum=(int*)((char*)d_out+(size_t)4*N);

  int NBn=(N+NT-1)/NT, nbE=(E+NT-1)/NT;
  int nbE2=(E+NT*2-1)/(NT*2);
  int nscan=in_sizes[0]*2; if(nscan>512) nscan=512;

  hipMemsetAsync(rowc,0,(size_t)N*sizeof(int),stream);
  k_probe  <<<1,64,0,stream>>>((const unsigned short*)x,nscan,stats);
  k_prep   <<<1024,NT,0,stream>>>(ea,idx,rowc,stats,E,N);
  k_node1  <<<NBn,NT,0,stream>>>(x,W1,as1,ad1,stats,als,ald,N);
  k_scan1  <<<NBn,NT,0,stream>>>(rowc,bsum,N);
  k_scan2  <<<1,1024,0,stream>>>(bsum,NBn);
  k_scan3  <<<NBn,NT,0,stream>>>(rowc,bsum,N);
  k_scatter<<<nbE,NT,0,stream>>>(idx,ea,We1,ae1,als,stats,rowc,csr,E,N);
  k_gather1<<<(N+15)/16,NT,0,stream>>>(csr,rowc,als,ald,x,W1,b1,W2,as2,ad2,We1,ae1,
                                       stats,invE,h1,h2,als,ald2,N);
  k_wprep  <<<1,NT,0,stream>>>(mw0,mb0,mw1,mb1,mw2,mb2,mw3,mb3,We2,ae2,stats,gw);
  hipMemsetAsync(den2,0,(size_t)N*sizeof(float),stream);
  hipMemsetAsync(acc2,0,(size_t)2*N*sizeof(float),stream);
  k_edge2  <<<nbE2,NT,0,stream>>>(idx,ea,h1,als,ald2,gw,h2,den2,acc2,stats,d_out,E,N);
  k_final  <<<NBn,NT,0,stream>>>(stats,invE,als,ald2,We2,ae2,h2,den2,acc2,bias2,d_out,N);
}

// Round 5
// 1159.311 us; speedup vs baseline: 1.2799x; 1.0468x over previous
//
#include <hip/hip_runtime.h>
#include <hip/hip_bf16.h>
#include <stdint.h>

typedef __hip_bfloat16 bf16;
typedef unsigned long long ull;
#define NT 256
#define EPT 4   // edges per thread in k_edge2

__device__ __forceinline__ float b2f(bf16 v){ return __bfloat162float(v); }
__device__ __forceinline__ bf16 f2b(float v){ return __float2bfloat16(v); }
__device__ __forceinline__ float lrelu(float a){ return a>0.f ? a : 0.2f*a; }
__device__ __forceinline__ float sanf(float v){ return __builtin_isfinite(v) ? v : -12345.f; }
__device__ __forceinline__ float us2f(unsigned short u){ return __uint_as_float(((unsigned)u)<<16); }
__device__ __forceinline__ unsigned short f2bu(float v){ bf16 b=f2b(v); unsigned short u; __builtin_memcpy(&u,&b,2); return u; }

// dtype-flexible input load: f32in ? float : bf16
__device__ __forceinline__ float ld(const void* p, size_t i, int f32in){
  return f32in ? ((const float*)p)[i] : b2f(((const bf16*)p)[i]);
}

__device__ __forceinline__ float waveReduceSum(float v){
#pragma unroll
  for(int o=32;o>0;o>>=1) v += __shfl_down(v,o,64);
  return v;
}

__device__ __forceinline__ unsigned clampi(int v, int n){
  unsigned u=(unsigned)v; return (u<(unsigned)n)?u:0u;
}

// vectorized bf16 h1 row load (16 ch = 4x 8B)
__device__ __forceinline__ void load_h1v(const bf16* h1, unsigned node, float* dst){
  const ull* p=(const ull*)(h1+(size_t)node*16);
#pragma unroll
  for(int q=0;q<4;q++){
    ull v=p[q];
    dst[q*4+0]=us2f((unsigned short)v);        dst[q*4+1]=us2f((unsigned short)(v>>16));
    dst[q*4+2]=us2f((unsigned short)(v>>32));  dst[q*4+3]=us2f((unsigned short)(v>>48));
  }
}
// x row (4 ch) load, dtype-flex
__device__ __forceinline__ void load_x4(const void* x, unsigned n, int f32in, float* o){
  if(f32in){ float4 v=((const float4*)x)[n]; o[0]=v.x;o[1]=v.y;o[2]=v.z;o[3]=v.w; }
  else{
    ull v=((const ull*)x)[n];
    o[0]=us2f((unsigned short)v);       o[1]=us2f((unsigned short)(v>>16));
    o[2]=us2f((unsigned short)(v>>32)); o[3]=us2f((unsigned short)(v>>48));
  }
}

// ---------------- K0: zero stats, detect input dtype -> ((int*)stats)[7]
__global__ __launch_bounds__(64) void k_probe(const unsigned short* __restrict__ xraw,
                                              int nscan, float* __restrict__ stats){
  int t=threadIdx.x;
  int bad=0;
  for(int k=t*8;k<t*8+8;k++){
    if(k<nscan){
      unsigned short u=xraw[k];
      unsigned ex=(u>>7)&0xFF;
      bool plaus = (ex==0u) || (ex>=97u && ex<=157u);
      if(!plaus) bad++;
    }
  }
#pragma unroll
  for(int o=32;o>0;o>>=1) bad += __shfl_down(bad,o,64);
  if(t==0){
    for(int i=0;i<7;i++) stats[i]=0.f;
    ((int*)stats)[7] = (bad>=8) ? 1 : 0;
  }
}

// ---------------- K1: histogram of destinations + edge_attr sums -> stats[0..2]
__global__ __launch_bounds__(NT) void k_prep(const void* __restrict__ ea,
                                             const int* __restrict__ idx,
                                             int* __restrict__ rowc,
                                             float* __restrict__ stats, int E, int N){
  const int f32in=((const int*)stats)[7];
  __shared__ float lds[16];
  float s0=0.f,s1=0.f,s2=0.f;
  for(size_t e=(size_t)blockIdx.x*NT+threadIdx.x; e<(size_t)E; e+=(size_t)gridDim.x*NT){
    s0+=ld(ea,e*3+0,f32in); s1+=ld(ea,e*3+1,f32in); s2+=ld(ea,e*3+2,f32in);
    unsigned d=clampi(idx[(size_t)E+e],N);
    atomicAdd(&rowc[d],1);
  }
  int lane=threadIdx.x&63, wv=threadIdx.x>>6;
  s0=waveReduceSum(s0); s1=waveReduceSum(s1); s2=waveReduceSum(s2);
  if(lane==0){ lds[wv*4+0]=s0; lds[wv*4+1]=s1; lds[wv*4+2]=s2; }
  __syncthreads();
  if(threadIdx.x==0){
    float a0=0,a1=0,a2=0;
    for(int w=0;w<NT/64;w++){ a0+=lds[w*4]; a1+=lds[w*4+1]; a2+=lds[w*4+2]; }
    atomicAdd(&stats[0],a0); atomicAdd(&stats[1],a1); atomicAdd(&stats[2],a2);
  }
}

// ---------------- K2: als/ald per node
__global__ __launch_bounds__(NT) void k_node1(
    const void* __restrict__ x, const void* __restrict__ W1,
    const void* __restrict__ as1, const void* __restrict__ ad1,
    const float* __restrict__ stats,
    float* __restrict__ als, float* __restrict__ ald, int N){
  const int f32in=((const int*)stats)[7];
  __shared__ float sW1[64], sas[16], sad[16];
  if(threadIdx.x<64) sW1[threadIdx.x]=ld(W1,threadIdx.x,f32in);
  if(threadIdx.x<16){ sas[threadIdx.x]=ld(as1,threadIdx.x,f32in); sad[threadIdx.x]=ld(ad1,threadIdx.x,f32in); }
  __syncthreads();
  int i=blockIdx.x*NT+threadIdx.x;
  if(i>=N) return;
  float xv[4]; load_x4(x,(unsigned)i,f32in,xv);
  float a_s=0.f,a_d=0.f;
#pragma unroll
  for(int j=0;j<16;j++){
    float v=xv[0]*sW1[j]+xv[1]*sW1[16+j]+xv[2]*sW1[32+j]+xv[3]*sW1[48+j];
    a_s+=v*sas[j]; a_d+=v*sad[j];
  }
  als[i]=a_s; ald[i]=a_d;
}

// ---------------- scan (3 kernels): rowc hist -> exclusive starts
__global__ __launch_bounds__(NT) void k_scan1(const int* __restrict__ rowc, int* __restrict__ bsum, int N){
  __shared__ int sm[NT];
  int i=blockIdx.x*NT+threadIdx.x;
  sm[threadIdx.x]=(i<N)?rowc[i]:0;
  __syncthreads();
  for(int o=NT/2;o>0;o>>=1){ if(threadIdx.x<o) sm[threadIdx.x]+=sm[threadIdx.x+o]; __syncthreads(); }
  if(threadIdx.x==0) bsum[blockIdx.x]=sm[0];
}
__global__ __launch_bounds__(1024) void k_scan2(int* __restrict__ bsum, int NB){
  __shared__ int sm[1024];
  int i=threadIdx.x;
  int v=(i<NB)?bsum[i]:0;
  sm[i]=v; __syncthreads();
  for(int o=1;o<1024;o<<=1){
    int t=(i>=o)?sm[i-o]:0; __syncthreads();
    sm[i]+=t; __syncthreads();
  }
  if(i<NB) bsum[i]=(i==0)?0:sm[i-1];
}
__global__ __launch_bounds__(NT) void k_scan3(int* __restrict__ rowc, const int* __restrict__ bsum, int N){
  __shared__ int sm[NT];
  int i=blockIdx.x*NT+threadIdx.x;
  int v=(i<N)?rowc[i]:0;
  sm[threadIdx.x]=v; __syncthreads();
  for(int o=1;o<NT;o<<=1){
    int t=(threadIdx.x>=o)?sm[threadIdx.x-o]:0; __syncthreads();
    sm[threadIdx.x]+=t; __syncthreads();
  }
  if(i<N) rowc[i]=bsum[blockIdx.x]+sm[threadIdx.x]-v;   // exclusive start
}

// ---------------- K3: scatter packed {src, alpha_partial} into CSR slots; rowc -> end
__global__ __launch_bounds__(NT) void k_scatter(
    const int* __restrict__ idx, const void* __restrict__ ea,
    const void* __restrict__ We1, const void* __restrict__ ae1,
    const float* __restrict__ als, const float* __restrict__ stats,
    int* __restrict__ rowc, ull* __restrict__ csr, int E, int N){
  const int f32in=((const int*)stats)[7];
  __shared__ float sve[3];
  if(threadIdx.x<3){
    float v=0.f;
    for(int j=0;j<16;j++) v+=ld(We1,threadIdx.x*16+j,f32in)*ld(ae1,j,f32in);
    sve[threadIdx.x]=v;
  }
  __syncthreads();
  int e=blockIdx.x*NT+threadIdx.x;
  if(e>=E) return;
  unsigned s=clampi(idx[e],N), d=clampi(idx[(size_t)E+e],N);
  float ap = als[s] + ld(ea,(size_t)e*3+0,f32in)*sve[0]
                    + ld(ea,(size_t)e*3+1,f32in)*sve[1]
                    + ld(ea,(size_t)e*3+2,f32in)*sve[2];
  int pos=atomicAdd(&rowc[d],1);
  csr[pos] = (ull)s | ((ull)__float_as_uint(ap)<<32);
}

// ---------------- K4: gather-aggregate layer-1 softmax; write h1(bf16), h2, als2, ald2
// 16 lanes per node; 4 nodes per wave; 16 nodes per block.
__global__ __launch_bounds__(NT) void k_gather1(
    const ull* __restrict__ csr, const int* __restrict__ rowe,
    const float* __restrict__ als, const float* __restrict__ ald,
    const void* __restrict__ x, const void* __restrict__ W1, const void* __restrict__ b1,
    const void* __restrict__ W2, const void* __restrict__ as2, const void* __restrict__ ad2,
    const void* __restrict__ We1, const void* __restrict__ ae1,
    const float* __restrict__ stats, float invE,
    bf16* __restrict__ h1, float* __restrict__ h2,
    float* __restrict__ als2, float* __restrict__ ald2, int N){
  const int f32in=((const int*)stats)[7];
  __shared__ float sW1[64], sb1[16], sW2[32], sas2[2], sad2[2], saea[1];
  if(threadIdx.x<64) sW1[threadIdx.x]=ld(W1,threadIdx.x,f32in);
  if(threadIdx.x<16) sb1[threadIdx.x]=ld(b1,threadIdx.x,f32in);
  if(threadIdx.x<32) sW2[threadIdx.x]=ld(W2,threadIdx.x,f32in);
  if(threadIdx.x<2){ sas2[threadIdx.x]=ld(as2,threadIdx.x,f32in); sad2[threadIdx.x]=ld(ad2,threadIdx.x,f32in); }
  if(threadIdx.x==0){
    float a=0.f;
    for(int k=0;k<3;k++){
      float v=0.f;
      for(int j=0;j<16;j++) v+=ld(We1,k*16+j,f32in)*ld(ae1,j,f32in);
      a+=stats[k]*v;
    }
    saea[0]=a*invE;
  }
  __syncthreads();
  int n=blockIdx.x*16+(threadIdx.x>>4);
  int c=threadIdx.x&15;
  if(n>=N) return;
  int end=rowe[n];
  int start=(n==0)?0:rowe[n-1];
  float aldn=ald[n], alsn=als[n];
  float aself=lrelu(alsn+aldn+saea[0]);
  float w0=sW1[c], w1=sW1[16+c], w2=sW1[32+c], w3=sW1[48+c];
  // phase A: segment max (strided over slots)
  float m=aself;
  for(int k=start+c;k<end;k+=16){
    float ap=__uint_as_float((unsigned)(csr[k]>>32));
    m=fmaxf(m,lrelu(ap+aldn));
  }
#pragma unroll
  for(int o=1;o<16;o<<=1) m=fmaxf(m,__shfl_xor(m,o,64));
  // self contribution
  float xv[4]; load_x4(x,(unsigned)n,f32in,xv);
  float hc_self=xv[0]*w0+xv[1]*w1+xv[2]*w2+xv[3]*w3;
  float exs=expf(fminf(aself-m,0.f));
  float den=exs, acc=exs*hc_self;
  // phase B: serial over slots, lane c = channel
  for(int k=start;k<end;k++){
    ull v=csr[k];
    unsigned src=(unsigned)(v&0xffffffffu);
    float ap=__uint_as_float((unsigned)(v>>32));
    float ex=expf(fminf(lrelu(ap+aldn)-m,0.f));
    den+=ex;
    float xs[4]; load_x4(x,src,f32in,xs);
    float hc=xs[0]*w0+xs[1]*w1+xs[2]*w2+xs[3]*w3;
    acc+=ex*hc;
  }
  float inv=1.f/(den+1e-16f);
  float h1c=acc*inv+sb1[c];
  h1[(size_t)n*16+c]=f2b(h1c);
  float r0=h1c*sW2[c*2+0], r1=h1c*sW2[c*2+1];
#pragma unroll
  for(int o=1;o<16;o<<=1){ r0+=__shfl_xor(r0,o,64); r1+=__shfl_xor(r1,o,64); }
  if(c==0){
    h2[(size_t)n*2+0]=r0; h2[(size_t)n*2+1]=r1;
    als2[n]=r0*sas2[0]+r1*sas2[1];
    ald2[n]=r0*sad2[0]+r1*sad2[1];
  }
}

// ---------------- K5: normalize all edge-MLP weights to f32 in global gw[1040]
__global__ __launch_bounds__(NT) void k_wprep(
    const void* mw0,const void* mb0,const void* mw1,const void* mb1,
    const void* mw2,const void* mb2,const void* mw3,const void* mb3,
    const void* We2,const void* ae2,
    const float* __restrict__ stats, float* __restrict__ gw){
  const int f32in=((const int*)stats)[7];
  for(int t=threadIdx.x;t<560;t+=NT) gw[t]=ld(mw0,t,f32in);
  for(int t=threadIdx.x;t<256;t+=NT) gw[576+t]=ld(mw1,t,f32in);
  for(int t=threadIdx.x;t<128;t+=NT) gw[848+t]=ld(mw2,t,f32in);
  if(threadIdx.x<32) gw[984+threadIdx.x]=ld(mw3,threadIdx.x,f32in);
  if(threadIdx.x<16){ gw[560+threadIdx.x]=ld(mb0,threadIdx.x,f32in); gw[832+threadIdx.x]=ld(mb1,threadIdx.x,f32in); }
  if(threadIdx.x<8) gw[976+threadIdx.x]=ld(mb2,threadIdx.x,f32in);
  if(threadIdx.x<4){
    gw[1016+threadIdx.x]=ld(mb3,threadIdx.x,f32in);
    gw[1020+threadIdx.x]=ld(We2,threadIdx.x*2+0,f32in)*ld(ae2,0,f32in)
                        +ld(We2,threadIdx.x*2+1,f32in)*ld(ae2,1,f32in);
  }
}

// Quad-edge MLP eval: one weight-row load feeds FOUR independent edges' FMAs.
// Per-output accumulation order over i2 unchanged per edge -> bit-identical.
__device__ __forceinline__ void mlp_eval_g4(const float z[EPT][35],
                                            const float* __restrict__ gw,
                                            float ev[EPT][4]){
  const float4* w4=(const float4*)gw;        // mw0: 35 rows x 16
  float t1[EPT][16];
  {
    const float4* b=(const float4*)(gw+560);
    float4 b0=b[0],b1=b[1],b2=b[2],b3=b[3];
#pragma unroll
    for(int u=0;u<EPT;u++){
      t1[u][0]=b0.x; t1[u][1]=b0.y; t1[u][2]=b0.z; t1[u][3]=b0.w;
      t1[u][4]=b1.x; t1[u][5]=b1.y; t1[u][6]=b1.z; t1[u][7]=b1.w;
      t1[u][8]=b2.x; t1[u][9]=b2.y; t1[u][10]=b2.z; t1[u][11]=b2.w;
      t1[u][12]=b3.x; t1[u][13]=b3.y; t1[u][14]=b3.z; t1[u][15]=b3.w;
    }
  }
#pragma unroll
  for(int i2=0;i2<35;i2++){
    float4 r0=w4[i2*4+0], r1=w4[i2*4+1], r2=w4[i2*4+2], r3=w4[i2*4+3];
#pragma unroll
    for(int u=0;u<EPT;u++){
      float a=z[u][i2];
      t1[u][0]+=a*r0.x; t1[u][1]+=a*r0.y; t1[u][2]+=a*r0.z; t1[u][3]+=a*r0.w;
      t1[u][4]+=a*r1.x; t1[u][5]+=a*r1.y; t1[u][6]+=a*r1.z; t1[u][7]+=a*r1.w;
      t1[u][8]+=a*r2.x; t1[u][9]+=a*r2.y; t1[u][10]+=a*r2.z; t1[u][11]+=a*r2.w;
      t1[u][12]+=a*r3.x; t1[u][13]+=a*r3.y; t1[u][14]+=a*r3.z; t1[u][15]+=a*r3.w;
    }
  }
#pragma unroll
  for(int u=0;u<EPT;u++)
#pragma unroll
    for(int j=0;j<16;j++) t1[u][j]=fmaxf(t1[u][j],0.f);

  const float4* w14=(const float4*)(gw+576); // mw1: 16 rows x 16
  float t2[EPT][16];
  {
    const float4* b=(const float4*)(gw+832);
    float4 b0=b[0],b1=b[1],b2=b[2],b3=b[3];
#pragma unroll
    for(int u=0;u<EPT;u++){
      t2[u][0]=b0.x; t2[u][1]=b0.y; t2[u][2]=b0.z; t2[u][3]=b0.w;
      t2[u][4]=b1.x; t2[u][5]=b1.y; t2[u][6]=b1.z; t2[u][7]=b1.w;
      t2[u][8]=b2.x; t2[u][9]=b2.y; t2[u][10]=b2.z; t2[u][11]=b2.w;
      t2[u][12]=b3.x; t2[u][13]=b3.y; t2[u][14]=b3.z; t2[u][15]=b3.w;
    }
  }
#pragma unroll
  for(int i2=0;i2<16;i2++){
    float4 r0=w14[i2*4+0], r1=w14[i2*4+1], r2=w14[i2*4+2], r3=w14[i2*4+3];
#pragma unroll
    for(int u=0;u<EPT;u++){
      float a=t1[u][i2];
      t2[u][0]+=a*r0.x; t2[u][1]+=a*r0.y; t2[u][2]+=a*r0.z; t2[u][3]+=a*r0.w;
      t2[u][4]+=a*r1.x; t2[u][5]+=a*r1.y; t2[u][6]+=a*r1.z; t2[u][7]+=a*r1.w;
      t2[u][8]+=a*r2.x; t2[u][9]+=a*r2.y; t2[u][10]+=a*r2.z; t2[u][11]+=a*r2.w;
      t2[u][12]+=a*r3.x; t2[u][13]+=a*r3.y; t2[u][14]+=a*r3.z; t2[u][15]+=a*r3.w;
    }
  }
#pragma unroll
  for(int u=0;u<EPT;u++)
#pragma unroll
    for(int j=0;j<16;j++) t2[u][j]=fmaxf(t2[u][j],0.f);

  const float4* w24=(const float4*)(gw+848); // mw2: 16 rows x 8
  float t3[EPT][8];
  {
    const float4* b=(const float4*)(gw+976);
    float4 b0=b[0],b1=b[1];
#pragma unroll
    for(int u=0;u<EPT;u++){
      t3[u][0]=b0.x; t3[u][1]=b0.y; t3[u][2]=b0.z; t3[u][3]=b0.w;
      t3[u][4]=b1.x; t3[u][5]=b1.y; t3[u][6]=b1.z; t3[u][7]=b1.w;
    }
  }
#pragma unroll
  for(int i2=0;i2<16;i2++){
    float4 r0=w24[i2*2+0], r1=w24[i2*2+1];
#pragma unroll
    for(int u=0;u<EPT;u++){
      float a=t2[u][i2];
      t3[u][0]+=a*r0.x; t3[u][1]+=a*r0.y; t3[u][2]+=a*r0.z; t3[u][3]+=a*r0.w;
      t3[u][4]+=a*r1.x; t3[u][5]+=a*r1.y; t3[u][6]+=a*r1.z; t3[u][7]+=a*r1.w;
    }
  }
#pragma unroll
  for(int u=0;u<EPT;u++)
#pragma unroll
    for(int j=0;j<8;j++) t3[u][j]=fmaxf(t3[u][j],0.f);

  const float4* w34=(const float4*)(gw+984); // mw3: 8 rows x 4
  {
    const float4* b=(const float4*)(gw+1016);
    float4 b0=b[0];
#pragma unroll
    for(int u=0;u<EPT;u++){ ev[u][0]=b0.x; ev[u][1]=b0.y; ev[u][2]=b0.z; ev[u][3]=b0.w; }
  }
#pragma unroll
  for(int i2=0;i2<8;i2++){
    float4 r0=w34[i2];
#pragma unroll
    for(int u=0;u<EPT;u++){
      float a=t3[u][i2];
      ev[u][0]+=a*r0.x; ev[u][1]+=a*r0.y; ev[u][2]+=a*r0.z; ev[u][3]+=a*r0.w;
    }
  }
}

// per-edge epilogue: out1 log_softmax store + layer-2 alpha accum
__device__ __forceinline__ void edge_epi(const float* ev, unsigned s, unsigned d, int e,
                                         const float* __restrict__ gw,
                                         const float* __restrict__ als2,
                                         const float* __restrict__ ald2,
                                         const float* __restrict__ h2,
                                         float* __restrict__ denom2, float* __restrict__ acc2,
                                         void* __restrict__ d_out, int f32in, int N){
  float m=fmaxf(fmaxf(ev[0],ev[1]),fmaxf(ev[2],ev[3]));
  float lse=m+logf(expf(ev[0]-m)+expf(ev[1]-m)+expf(ev[2]-m)+expf(ev[3]-m));
  if(f32in){
    float4 o; o.x=sanf(ev[0]-lse); o.y=sanf(ev[1]-lse); o.z=sanf(ev[2]-lse); o.w=sanf(ev[3]-lse);
    ((float4*)((float*)d_out+(size_t)2*N))[e]=o;
  }else{
    ull o = (ull)f2bu(sanf(ev[0]-lse))
          | ((ull)f2bu(sanf(ev[1]-lse))<<16)
          | ((ull)f2bu(sanf(ev[2]-lse))<<32)
          | ((ull)f2bu(sanf(ev[3]-lse))<<48);
    ((ull*)((bf16*)d_out+(size_t)2*N))[e]=o;
  }
  const float* s_ve2=gw+1020;
  float adot=ev[0]*s_ve2[0]+ev[1]*s_ve2[1]+ev[2]*s_ve2[2]+ev[3]*s_ve2[3];
  float a2=sanf(lrelu(als2[s]+ald2[d]+adot));
  float ex=expf(fminf(a2,80.f));
  float2 h2s=((const float2*)h2)[s];
  atomicAdd(&denom2[d],ex);
  atomicAdd(&acc2[(size_t)d*2+0],ex*h2s.x);
  atomicAdd(&acc2[(size_t)d*2+1],ex*h2s.y);
}

// ---------------- K6: edge MLP (EPT edges/thread) + out1 + mean(e) + fused layer-2 accum
__global__ __launch_bounds__(NT,1) void k_edge2(
    const int* __restrict__ idx, const void* __restrict__ ea,
    const bf16* __restrict__ h1,
    const float* __restrict__ als2, const float* __restrict__ ald2,
    const float* __restrict__ gw,
    const float* __restrict__ h2,
    float* __restrict__ denom2, float* __restrict__ acc2,
    float* __restrict__ stats, void* __restrict__ d_out, int E, int N){
  const int f32in=((const int*)stats)[7];
  __shared__ float s_red[16];
  size_t base=(size_t)blockIdx.x*(NT*EPT)+threadIdx.x;
  int e[EPT]; bool v[EPT]; int es[EPT]; unsigned s[EPT], d[EPT];
#pragma unroll
  for(int u=0;u<EPT;u++){
    e[u]=(int)(base+(size_t)u*NT);
    v[u]=e[u]<E;
    es[u]=v[u]?e[u]:0;
    s[u]=clampi(idx[es[u]],N);
    d[u]=clampi(idx[(size_t)E+es[u]],N);
  }
  float z[EPT][35];
#pragma unroll
  for(int u=0;u<EPT;u++){
    load_h1v(h1,s[u],z[u]);
    load_h1v(h1,d[u],z[u]+19);
    z[u][16]=ld(ea,(size_t)es[u]*3+0,f32in);
    z[u][17]=ld(ea,(size_t)es[u]*3+1,f32in);
    z[u][18]=ld(ea,(size_t)es[u]*3+2,f32in);
  }
  float ev[EPT][4];
  mlp_eval_g4(z,gw,ev);
  float c0=0.f,c1=0.f,c2=0.f,c3=0.f;
#pragma unroll
  for(int u=0;u<EPT;u++){
    if(v[u]){
      edge_epi(ev[u],s[u],d[u],e[u],gw,als2,ald2,h2,denom2,acc2,d_out,f32in,N);
      c0+=ev[u][0]; c1+=ev[u][1]; c2+=ev[u][2]; c3+=ev[u][3];
    }
  }
  int lane=threadIdx.x&63, wv=threadIdx.x>>6;
  c0=waveReduceSum(c0); c1=waveReduceSum(c1); c2=waveReduceSum(c2); c3=waveReduceSum(c3);
  __syncthreads();
  if(lane==0){ s_red[wv*4]=c0; s_red[wv*4+1]=c1; s_red[wv*4+2]=c2; s_red[wv*4+3]=c3; }
  __syncthreads();
  if(threadIdx.x==0){
    float a0=0,a1=0,a2=0,a3=0;
    for(int w=0;w<NT/64;w++){ a0+=s_red[w*4]; a1+=s_red[w*4+1]; a2+=s_red[w*4+2]; a3+=s_red[w*4+3]; }
    atomicAdd(&stats[3],a0); atomicAdd(&stats[4],a1); atomicAdd(&stats[5],a2); atomicAdd(&stats[6],a3);
  }
}

// ---------------- K7: fused self-loop fold + layer-2 epilogue + out0 log_softmax
__global__ __launch_bounds__(NT) void k_final(
    const float* __restrict__ stats, float invE,
    const float* __restrict__ als2, const float* __restrict__ ald2,
    const void* __restrict__ We2, const void* __restrict__ ae2,
    const float* __restrict__ h2,
    const float* __restrict__ denom2, const float* __restrict__ acc2,
    const void* __restrict__ bias2, void* __restrict__ d_out, int N){
  const int f32in=((const int*)stats)[7];
  __shared__ float s_ve2[4], s_b2[2];
  if(threadIdx.x<4)
    s_ve2[threadIdx.x]=ld(We2,threadIdx.x*2+0,f32in)*ld(ae2,0,f32in)
                      +ld(We2,threadIdx.x*2+1,f32in)*ld(ae2,1,f32in);
  if(threadIdx.x<2) s_b2[threadIdx.x]=ld(bias2,threadIdx.x,f32in);
  __syncthreads();
  int i=blockIdx.x*NT+threadIdx.x;
  if(i>=N) return;
  float adot=(stats[3]*s_ve2[0]+stats[4]*s_ve2[1]+stats[5]*s_ve2[2]+stats[6]*s_ve2[3])*invE;
  float self=lrelu(als2[i]+ald2[i]+adot);
  float ex=expf(fminf(self,80.f));
  float den=denom2[i]+ex;
  float inv=1.f/(den+1e-16f);
  float o0=(acc2[(size_t)i*2+0]+ex*h2[(size_t)i*2+0])*inv+s_b2[0];
  float o1=(acc2[(size_t)i*2+1]+ex*h2[(size_t)i*2+1])*inv+s_b2[1];
  float m=fmaxf(o0,o1);
  float lse=m+logf(expf(o0-m)+expf(o1-m));
  float r0=sanf(o0-lse), r1=sanf(o1-lse);
  if(f32in){
    float* o=(float*)d_out;
    o[(size_t)i*2+0]=r0; o[(size_t)i*2+1]=r1;
  }else{
    bf16* o=(bf16*)d_out;
    o[(size_t)i*2+0]=f2b(r0); o[(size_t)i*2+1]=f2b(r1);
  }
}

extern "C" void kernel_launch(void* const* d_in, const int* in_sizes, int n_in,
                              void* d_out, int out_size, void* d_ws, size_t ws_size,
                              hipStream_t stream){
  const void* x   =d_in[0];
  const void* ea  =d_in[1];
  const void* W1  =d_in[2];
  const void* as1 =d_in[3];
  const void* ad1 =d_in[4];
  const void* We1 =d_in[5];
  const void* ae1 =d_in[6];
  const void* b1  =d_in[7];
  const void* mw0 =d_in[8];
  const void* mb0 =d_in[9];
  const void* mw1 =d_in[10];
  const void* mb1 =d_in[11];
  const void* mw2 =d_in[12];
  const void* mb2 =d_in[13];
  const void* mw3 =d_in[14];
  const void* mb3 =d_in[15];
  const void* W2  =d_in[16];
  const void* as2 =d_in[17];
  const void* ad2 =d_in[18];
  const void* We2 =d_in[19];
  const void* ae2 =d_in[20];
  const void* bias2=d_in[21];
  const int*  idx =(const int*)d_in[22];

  int N=in_sizes[0]/4;
  int E=in_sizes[1]/3;
  float invE=1.f/(float)E;

  float*    F     =(float*)d_ws;
  float*    stats =F;                         // 8
  float*    als   =F+8;                       // N   (als2 aliases after gather1)
  float*    ald   =als+N;                     // N   (den2 aliases after gather1)
  float*    ald2  =ald+N;                     // N
  int*      rowc  =(int*)(ald2+N);            // N   (hist -> start -> end; dead after gather1, then gw)
  bf16*     h1    =(bf16*)(rowc+N);           // 16N bf16 = 8N floats
  float*    h2    =(float*)(h1+(size_t)16*N); // 2N
  float*    acc2  =h2+(size_t)2*N;            // 2N
  float*    den2  =ald;
  // gw: 1040 f32 in the dead rowc region, 16B-aligned for float4 loads
  float*    gw    =(float*)((((uintptr_t)rowc)+15)&~(uintptr_t)15);

  ull* csr =(ull*)((char*)d_out+(size_t)4*N);
  int* bsum=(int*)((char*)d_out+(size_t)4*N);

  int NBn=(N+NT-1)/NT, nbE=(E+NT-1)/NT;
  int nbE4=(E+NT*EPT-1)/(NT*EPT);
  int nscan=in_sizes[0]*2; if(nscan>512) nscan=512;

  hipMemsetAsync(rowc,0,(size_t)N*sizeof(int),stream);
  k_probe  <<<1,64,0,stream>>>((const unsigned short*)x,nscan,stats);
  k_prep   <<<1024,NT,0,stream>>>(ea,idx,rowc,stats,E,N);
  k_node1  <<<NBn,NT,0,stream>>>(x,W1,as1,ad1,stats,als,ald,N);
  k_scan1  <<<NBn,NT,0,stream>>>(rowc,bsum,N);
  k_scan2  <<<1,1024,0,stream>>>(bsum,NBn);
  k_scan3  <<<NBn,NT,0,stream>>>(rowc,bsum,N);
  k_scatter<<<nbE,NT,0,stream>>>(idx,ea,We1,ae1,als,stats,rowc,csr,E,N);
  k_gather1<<<(N+15)/16,NT,0,stream>>>(csr,rowc,als,ald,x,W1,b1,W2,as2,ad2,We1,ae1,
                                       stats,invE,h1,h2,als,ald2,N);
  k_wprep  <<<1,NT,0,stream>>>(mw0,mb0,mw1,mb1,mw2,mb2,mw3,mb3,We2,ae2,stats,gw);
  hipMemsetAsync(den2,0,(size_t)N*sizeof(float),stream);
  hipMemsetAsync(acc2,0,(size_t)2*N*sizeof(float),stream);
  k_edge2  <<<nbE4,NT,0,stream>>>(idx,ea,h1,als,ald2,gw,h2,den2,acc2,stats,d_out,E,N);
  k_final  <<<NBn,NT,0,stream>>>(stats,invE,als,ald2,We2,ae2,h2,den2,acc2,bias2,d_out,N);
}

// Round 6
// 1133.919 us; speedup vs baseline: 1.3085x; 1.0224x over previous
//
#include <hip/hip_runtime.h>
#include <hip/hip_bf16.h>
#include <stdint.h>

typedef __hip_bfloat16 bf16;
typedef unsigned long long ull;
#define NT 256
#define EPT 4   // edges per thread in k_edge2 variants

__device__ __forceinline__ float b2f(bf16 v){ return __bfloat162float(v); }
__device__ __forceinline__ bf16 f2b(float v){ return __float2bfloat16(v); }
__device__ __forceinline__ float lrelu(float a){ return a>0.f ? a : 0.2f*a; }
__device__ __forceinline__ float sanf(float v){ return __builtin_isfinite(v) ? v : -12345.f; }
__device__ __forceinline__ float us2f(unsigned short u){ return __uint_as_float(((unsigned)u)<<16); }
__device__ __forceinline__ unsigned short f2bu(float v){ bf16 b=f2b(v); unsigned short u; __builtin_memcpy(&u,&b,2); return u; }

__device__ __forceinline__ float ld(const void* p, size_t i, int f32in){
  return f32in ? ((const float*)p)[i] : b2f(((const bf16*)p)[i]);
}

__device__ __forceinline__ float waveReduceSum(float v){
#pragma unroll
  for(int o=32;o>0;o>>=1) v += __shfl_down(v,o,64);
  return v;
}

__device__ __forceinline__ unsigned clampi(int v, int n){
  unsigned u=(unsigned)v; return (u<(unsigned)n)?u:0u;
}

// vectorized bf16 h1 row load (16 ch = 4x 8B)
__device__ __forceinline__ void load_h1v(const bf16* h1, unsigned node, float* dst){
  const ull* p=(const ull*)(h1+(size_t)node*16);
#pragma unroll
  for(int q=0;q<4;q++){
    ull v=p[q];
    dst[q*4+0]=us2f((unsigned short)v);        dst[q*4+1]=us2f((unsigned short)(v>>16));
    dst[q*4+2]=us2f((unsigned short)(v>>32));  dst[q*4+3]=us2f((unsigned short)(v>>48));
  }
}
__device__ __forceinline__ void load_x4(const void* x, unsigned n, int f32in, float* o){
  if(f32in){ float4 v=((const float4*)x)[n]; o[0]=v.x;o[1]=v.y;o[2]=v.z;o[3]=v.w; }
  else{
    ull v=((const ull*)x)[n];
    o[0]=us2f((unsigned short)v);       o[1]=us2f((unsigned short)(v>>16));
    o[2]=us2f((unsigned short)(v>>32)); o[3]=us2f((unsigned short)(v>>48));
  }
}

// ---------------- K0: zero stats, detect input dtype -> ((int*)stats)[7]
__global__ __launch_bounds__(64) void k_probe(const unsigned short* __restrict__ xraw,
                                              int nscan, float* __restrict__ stats){
  int t=threadIdx.x;
  int bad=0;
  for(int k=t*8;k<t*8+8;k++){
    if(k<nscan){
      unsigned short u=xraw[k];
      unsigned ex=(u>>7)&0xFF;
      bool plaus = (ex==0u) || (ex>=97u && ex<=157u);
      if(!plaus) bad++;
    }
  }
#pragma unroll
  for(int o=32;o>0;o>>=1) bad += __shfl_down(bad,o,64);
  if(t==0){
    for(int i=0;i<7;i++) stats[i]=0.f;
    ((int*)stats)[7] = (bad>=8) ? 1 : 0;
  }
}

// ---------------- K1: histogram of destinations + edge_attr sums -> stats[0..2]
__global__ __launch_bounds__(NT) void k_prep(const void* __restrict__ ea,
                                             const int* __restrict__ idx,
                                             int* __restrict__ rowc,
                                             float* __restrict__ stats, int E, int N){
  const int f32in=((const int*)stats)[7];
  __shared__ float lds[16];
  float s0=0.f,s1=0.f,s2=0.f;
  for(size_t e=(size_t)blockIdx.x*NT+threadIdx.x; e<(size_t)E; e+=(size_t)gridDim.x*NT){
    s0+=ld(ea,e*3+0,f32in); s1+=ld(ea,e*3+1,f32in); s2+=ld(ea,e*3+2,f32in);
    unsigned d=clampi(idx[(size_t)E+e],N);
    atomicAdd(&rowc[d],1);
  }
  int lane=threadIdx.x&63, wv=threadIdx.x>>6;
  s0=waveReduceSum(s0); s1=waveReduceSum(s1); s2=waveReduceSum(s2);
  if(lane==0){ lds[wv*4+0]=s0; lds[wv*4+1]=s1; lds[wv*4+2]=s2; }
  __syncthreads();
  if(threadIdx.x==0){
    float a0=0,a1=0,a2=0;
    for(int w=0;w<NT/64;w++){ a0+=lds[w*4]; a1+=lds[w*4+1]; a2+=lds[w*4+2]; }
    atomicAdd(&stats[0],a0); atomicAdd(&stats[1],a1); atomicAdd(&stats[2],a2);
  }
}

// ---------------- K2: als/ald per node
__global__ __launch_bounds__(NT) void k_node1(
    const void* __restrict__ x, const void* __restrict__ W1,
    const void* __restrict__ as1, const void* __restrict__ ad1,
    const float* __restrict__ stats,
    float* __restrict__ als, float* __restrict__ ald, int N){
  const int f32in=((const int*)stats)[7];
  __shared__ float sW1[64], sas[16], sad[16];
  if(threadIdx.x<64) sW1[threadIdx.x]=ld(W1,threadIdx.x,f32in);
  if(threadIdx.x<16){ sas[threadIdx.x]=ld(as1,threadIdx.x,f32in); sad[threadIdx.x]=ld(ad1,threadIdx.x,f32in); }
  __syncthreads();
  int i=blockIdx.x*NT+threadIdx.x;
  if(i>=N) return;
  float xv[4]; load_x4(x,(unsigned)i,f32in,xv);
  float a_s=0.f,a_d=0.f;
#pragma unroll
  for(int j=0;j<16;j++){
    float v=xv[0]*sW1[j]+xv[1]*sW1[16+j]+xv[2]*sW1[32+j]+xv[3]*sW1[48+j];
    a_s+=v*sas[j]; a_d+=v*sad[j];
  }
  als[i]=a_s; ald[i]=a_d;
}

// ---------------- scan (3 kernels): rowc hist -> exclusive starts
__global__ __launch_bounds__(NT) void k_scan1(const int* __restrict__ rowc, int* __restrict__ bsum, int N){
  __shared__ int sm[NT];
  int i=blockIdx.x*NT+threadIdx.x;
  sm[threadIdx.x]=(i<N)?rowc[i]:0;
  __syncthreads();
  for(int o=NT/2;o>0;o>>=1){ if(threadIdx.x<o) sm[threadIdx.x]+=sm[threadIdx.x+o]; __syncthreads(); }
  if(threadIdx.x==0) bsum[blockIdx.x]=sm[0];
}
__global__ __launch_bounds__(1024) void k_scan2(int* __restrict__ bsum, int NB){
  __shared__ int sm[1024];
  int i=threadIdx.x;
  int v=(i<NB)?bsum[i]:0;
  sm[i]=v; __syncthreads();
  for(int o=1;o<1024;o<<=1){
    int t=(i>=o)?sm[i-o]:0; __syncthreads();
    sm[i]+=t; __syncthreads();
  }
  if(i<NB) bsum[i]=(i==0)?0:sm[i-1];
}
__global__ __launch_bounds__(NT) void k_scan3(int* __restrict__ rowc, const int* __restrict__ bsum, int N){
  __shared__ int sm[NT];
  int i=blockIdx.x*NT+threadIdx.x;
  int v=(i<N)?rowc[i]:0;
  sm[threadIdx.x]=v; __syncthreads();
  for(int o=1;o<NT;o<<=1){
    int t=(threadIdx.x>=o)?sm[threadIdx.x-o]:0; __syncthreads();
    sm[threadIdx.x]+=t; __syncthreads();
  }
  if(i<N) rowc[i]=bsum[blockIdx.x]+sm[threadIdx.x]-v;   // exclusive start
}

// ---------------- K3: scatter packed {src, alpha_partial} into CSR slots; rowc -> end
__global__ __launch_bounds__(NT) void k_scatter(
    const int* __restrict__ idx, const void* __restrict__ ea,
    const void* __restrict__ We1, const void* __restrict__ ae1,
    const float* __restrict__ als, const float* __restrict__ stats,
    int* __restrict__ rowc, ull* __restrict__ csr, int E, int N){
  const int f32in=((const int*)stats)[7];
  __shared__ float sve[3];
  if(threadIdx.x<3){
    float v=0.f;
    for(int j=0;j<16;j++) v+=ld(We1,threadIdx.x*16+j,f32in)*ld(ae1,j,f32in);
    sve[threadIdx.x]=v;
  }
  __syncthreads();
  int e=blockIdx.x*NT+threadIdx.x;
  if(e>=E) return;
  unsigned s=clampi(idx[e],N), d=clampi(idx[(size_t)E+e],N);
  float ap = als[s] + ld(ea,(size_t)e*3+0,f32in)*sve[0]
                    + ld(ea,(size_t)e*3+1,f32in)*sve[1]
                    + ld(ea,(size_t)e*3+2,f32in)*sve[2];
  int pos=atomicAdd(&rowc[d],1);
  csr[pos] = (ull)s | ((ull)__float_as_uint(ap)<<32);
}

// ---------------- K4: gather-aggregate layer-1 softmax; write h1(bf16), h2, als2, ald2
__global__ __launch_bounds__(NT) void k_gather1(
    const ull* __restrict__ csr, const int* __restrict__ rowe,
    const float* __restrict__ als, const float* __restrict__ ald,
    const void* __restrict__ x, const void* __restrict__ W1, const void* __restrict__ b1,
    const void* __restrict__ W2, const void* __restrict__ as2, const void* __restrict__ ad2,
    const void* __restrict__ We1, const void* __restrict__ ae1,
    const float* __restrict__ stats, float invE,
    bf16* __restrict__ h1, float* __restrict__ h2,
    float* __restrict__ als2, float* __restrict__ ald2, int N){
  const int f32in=((const int*)stats)[7];
  __shared__ float sW1[64], sb1[16], sW2[32], sas2[2], sad2[2], saea[1];
  if(threadIdx.x<64) sW1[threadIdx.x]=ld(W1,threadIdx.x,f32in);
  if(threadIdx.x<16) sb1[threadIdx.x]=ld(b1,threadIdx.x,f32in);
  if(threadIdx.x<32) sW2[threadIdx.x]=ld(W2,threadIdx.x,f32in);
  if(threadIdx.x<2){ sas2[threadIdx.x]=ld(as2,threadIdx.x,f32in); sad2[threadIdx.x]=ld(ad2,threadIdx.x,f32in); }
  if(threadIdx.x==0){
    float a=0.f;
    for(int k=0;k<3;k++){
      float v=0.f;
      for(int j=0;j<16;j++) v+=ld(We1,k*16+j,f32in)*ld(ae1,j,f32in);
      a+=stats[k]*v;
    }
    saea[0]=a*invE;
  }
  __syncthreads();
  int n=blockIdx.x*16+(threadIdx.x>>4);
  int c=threadIdx.x&15;
  if(n>=N) return;
  int end=rowe[n];
  int start=(n==0)?0:rowe[n-1];
  float aldn=ald[n], alsn=als[n];
  float aself=lrelu(alsn+aldn+saea[0]);
  float w0=sW1[c], w1=sW1[16+c], w2=sW1[32+c], w3=sW1[48+c];
  float m=aself;
  for(int k=start+c;k<end;k+=16){
    float ap=__uint_as_float((unsigned)(csr[k]>>32));
    m=fmaxf(m,lrelu(ap+aldn));
  }
#pragma unroll
  for(int o=1;o<16;o<<=1) m=fmaxf(m,__shfl_xor(m,o,64));
  float xv[4]; load_x4(x,(unsigned)n,f32in,xv);
  float hc_self=xv[0]*w0+xv[1]*w1+xv[2]*w2+xv[3]*w3;
  float exs=expf(fminf(aself-m,0.f));
  float den=exs, acc=exs*hc_self;
  for(int k=start;k<end;k++){
    ull v=csr[k];
    unsigned src=(unsigned)(v&0xffffffffu);
    float ap=__uint_as_float((unsigned)(v>>32));
    float ex=expf(fminf(lrelu(ap+aldn)-m,0.f));
    den+=ex;
    float xs[4]; load_x4(x,src,f32in,xs);
    float hc=xs[0]*w0+xs[1]*w1+xs[2]*w2+xs[3]*w3;
    acc+=ex*hc;
  }
  float inv=1.f/(den+1e-16f);
  float h1c=acc*inv+sb1[c];
  h1[(size_t)n*16+c]=f2b(h1c);
  float r0=h1c*sW2[c*2+0], r1=h1c*sW2[c*2+1];
#pragma unroll
  for(int o=1;o<16;o<<=1){ r0+=__shfl_xor(r0,o,64); r1+=__shfl_xor(r1,o,64); }
  if(c==0){
    h2[(size_t)n*2+0]=r0; h2[(size_t)n*2+1]=r1;
    als2[n]=r0*sas2[0]+r1*sas2[1];
    ald2[n]=r0*sad2[0]+r1*sad2[1];
  }
}

// ---------------- K5: normalize all edge-MLP weights to f32 in global gw[1040]
__global__ __launch_bounds__(NT) void k_wprep(
    const void* mw0,const void* mb0,const void* mw1,const void* mb1,
    const void* mw2,const void* mb2,const void* mw3,const void* mb3,
    const void* We2,const void* ae2,
    const float* __restrict__ stats, float* __restrict__ gw){
  const int f32in=((const int*)stats)[7];
  for(int t=threadIdx.x;t<560;t+=NT) gw[t]=ld(mw0,t,f32in);
  for(int t=threadIdx.x;t<256;t+=NT) gw[576+t]=ld(mw1,t,f32in);
  for(int t=threadIdx.x;t<128;t+=NT) gw[848+t]=ld(mw2,t,f32in);
  if(threadIdx.x<32) gw[984+threadIdx.x]=ld(mw3,threadIdx.x,f32in);
  if(threadIdx.x<16){ gw[560+threadIdx.x]=ld(mb0,threadIdx.x,f32in); gw[832+threadIdx.x]=ld(mb1,threadIdx.x,f32in); }
  if(threadIdx.x<8) gw[976+threadIdx.x]=ld(mb2,threadIdx.x,f32in);
  if(threadIdx.x<4){
    gw[1016+threadIdx.x]=ld(mb3,threadIdx.x,f32in);
    gw[1020+threadIdx.x]=ld(We2,threadIdx.x*2+0,f32in)*ld(ae2,0,f32in)
                        +ld(We2,threadIdx.x*2+1,f32in)*ld(ae2,1,f32in);
  }
}

// ---------------- K5b: per-node L0 precompute:
// u_s[n] = b0 + h1[n] @ mw0[0:16,:]   (bias folded in, matches reference prefix order)
// u_d[n] =      h1[n] @ mw0[19:35,:]
__global__ __launch_bounds__(NT) void k_upre(
    const bf16* __restrict__ h1, const float* __restrict__ gw,
    float* __restrict__ us, float* __restrict__ ud, int N){
  int n=blockIdx.x*NT+threadIdx.x;
  if(n>=N) return;
  float h[16]; load_h1v(h1,(unsigned)n,h);
  const float4* w4=(const float4*)gw;
  float4 a0,a1,a2,a3;
  { const float4* b=(const float4*)(gw+560); a0=b[0]; a1=b[1]; a2=b[2]; a3=b[3]; }
#pragma unroll
  for(int i=0;i<16;i++){
    float z=h[i];
    float4 r0=w4[i*4+0],r1=w4[i*4+1],r2=w4[i*4+2],r3=w4[i*4+3];
    a0.x+=z*r0.x; a0.y+=z*r0.y; a0.z+=z*r0.z; a0.w+=z*r0.w;
    a1.x+=z*r1.x; a1.y+=z*r1.y; a1.z+=z*r1.z; a1.w+=z*r1.w;
    a2.x+=z*r2.x; a2.y+=z*r2.y; a2.z+=z*r2.z; a2.w+=z*r2.w;
    a3.x+=z*r3.x; a3.y+=z*r3.y; a3.z+=z*r3.z; a3.w+=z*r3.w;
  }
  float4* po=(float4*)(us+(size_t)n*16);
  po[0]=a0; po[1]=a1; po[2]=a2; po[3]=a3;
  float4 c0=make_float4(0,0,0,0), c1=c0, c2=c0, c3=c0;
#pragma unroll
  for(int i=0;i<16;i++){
    float z=h[i];
    int r=19+i;
    float4 r0=w4[r*4+0],r1=w4[r*4+1],r2=w4[r*4+2],r3=w4[r*4+3];
    c0.x+=z*r0.x; c0.y+=z*r0.y; c0.z+=z*r0.z; c0.w+=z*r0.w;
    c1.x+=z*r1.x; c1.y+=z*r1.y; c1.z+=z*r1.z; c1.w+=z*r1.w;
    c2.x+=z*r2.x; c2.y+=z*r2.y; c2.z+=z*r2.z; c2.w+=z*r2.w;
    c3.x+=z*r3.x; c3.y+=z*r3.y; c3.z+=z*r3.z; c3.w+=z*r3.w;
  }
  float4* pd=(float4*)(ud+(size_t)n*16);
  pd[0]=c0; pd[1]=c1; pd[2]=c2; pd[3]=c3;
}

// ---------------- shared MLP tail: relu(t1) -> L1 -> L2 -> L3 (EPT-wide)
__device__ __forceinline__ void mlp_tail4(float t1[EPT][16],
                                          const float* __restrict__ gw,
                                          float ev[EPT][4]){
#pragma unroll
  for(int u=0;u<EPT;u++)
#pragma unroll
    for(int j=0;j<16;j++) t1[u][j]=fmaxf(t1[u][j],0.f);

  const float4* w14=(const float4*)(gw+576); // mw1: 16 rows x 16
  float t2[EPT][16];
  {
    const float4* b=(const float4*)(gw+832);
    float4 b0=b[0],b1=b[1],b2=b[2],b3=b[3];
#pragma unroll
    for(int u=0;u<EPT;u++){
      t2[u][0]=b0.x; t2[u][1]=b0.y; t2[u][2]=b0.z; t2[u][3]=b0.w;
      t2[u][4]=b1.x; t2[u][5]=b1.y; t2[u][6]=b1.z; t2[u][7]=b1.w;
      t2[u][8]=b2.x; t2[u][9]=b2.y; t2[u][10]=b2.z; t2[u][11]=b2.w;
      t2[u][12]=b3.x; t2[u][13]=b3.y; t2[u][14]=b3.z; t2[u][15]=b3.w;
    }
  }
#pragma unroll
  for(int i2=0;i2<16;i2++){
    float4 r0=w14[i2*4+0], r1=w14[i2*4+1], r2=w14[i2*4+2], r3=w14[i2*4+3];
#pragma unroll
    for(int u=0;u<EPT;u++){
      float a=t1[u][i2];
      t2[u][0]+=a*r0.x; t2[u][1]+=a*r0.y; t2[u][2]+=a*r0.z; t2[u][3]+=a*r0.w;
      t2[u][4]+=a*r1.x; t2[u][5]+=a*r1.y; t2[u][6]+=a*r1.z; t2[u][7]+=a*r1.w;
      t2[u][8]+=a*r2.x; t2[u][9]+=a*r2.y; t2[u][10]+=a*r2.z; t2[u][11]+=a*r2.w;
      t2[u][12]+=a*r3.x; t2[u][13]+=a*r3.y; t2[u][14]+=a*r3.z; t2[u][15]+=a*r3.w;
    }
  }
#pragma unroll
  for(int u=0;u<EPT;u++)
#pragma unroll
    for(int j=0;j<16;j++) t2[u][j]=fmaxf(t2[u][j],0.f);

  const float4* w24=(const float4*)(gw+848); // mw2: 16 rows x 8
  float t3[EPT][8];
  {
    const float4* b=(const float4*)(gw+976);
    float4 b0=b[0],b1=b[1];
#pragma unroll
    for(int u=0;u<EPT;u++){
      t3[u][0]=b0.x; t3[u][1]=b0.y; t3[u][2]=b0.z; t3[u][3]=b0.w;
      t3[u][4]=b1.x; t3[u][5]=b1.y; t3[u][6]=b1.z; t3[u][7]=b1.w;
    }
  }
#pragma unroll
  for(int i2=0;i2<16;i2++){
    float4 r0=w24[i2*2+0], r1=w24[i2*2+1];
#pragma unroll
    for(int u=0;u<EPT;u++){
      float a=t2[u][i2];
      t3[u][0]+=a*r0.x; t3[u][1]+=a*r0.y; t3[u][2]+=a*r0.z; t3[u][3]+=a*r0.w;
      t3[u][4]+=a*r1.x; t3[u][5]+=a*r1.y; t3[u][6]+=a*r1.z; t3[u][7]+=a*r1.w;
    }
  }
#pragma unroll
  for(int u=0;u<EPT;u++)
#pragma unroll
    for(int j=0;j<8;j++) t3[u][j]=fmaxf(t3[u][j],0.f);

  const float4* w34=(const float4*)(gw+984); // mw3: 8 rows x 4
  {
    const float4* b=(const float4*)(gw+1016);
    float4 b0=b[0];
#pragma unroll
    for(int u=0;u<EPT;u++){ ev[u][0]=b0.x; ev[u][1]=b0.y; ev[u][2]=b0.z; ev[u][3]=b0.w; }
  }
#pragma unroll
  for(int i2=0;i2<8;i2++){
    float4 r0=w34[i2];
#pragma unroll
    for(int u=0;u<EPT;u++){
      float a=t3[u][i2];
      ev[u][0]+=a*r0.x; ev[u][1]+=a*r0.y; ev[u][2]+=a*r0.z; ev[u][3]+=a*r0.w;
    }
  }
}

// fallback full L0 head (R5 behavior)
__device__ __forceinline__ void mlp_head_full4(const float z[EPT][35],
                                               const float* __restrict__ gw,
                                               float t1[EPT][16]){
  const float4* w4=(const float4*)gw;
  {
    const float4* b=(const float4*)(gw+560);
    float4 b0=b[0],b1=b[1],b2=b[2],b3=b[3];
#pragma unroll
    for(int u=0;u<EPT;u++){
      t1[u][0]=b0.x; t1[u][1]=b0.y; t1[u][2]=b0.z; t1[u][3]=b0.w;
      t1[u][4]=b1.x; t1[u][5]=b1.y; t1[u][6]=b1.z; t1[u][7]=b1.w;
      t1[u][8]=b2.x; t1[u][9]=b2.y; t1[u][10]=b2.z; t1[u][11]=b2.w;
      t1[u][12]=b3.x; t1[u][13]=b3.y; t1[u][14]=b3.z; t1[u][15]=b3.w;
    }
  }
#pragma unroll
  for(int i2=0;i2<35;i2++){
    float4 r0=w4[i2*4+0], r1=w4[i2*4+1], r2=w4[i2*4+2], r3=w4[i2*4+3];
#pragma unroll
    for(int u=0;u<EPT;u++){
      float a=z[u][i2];
      t1[u][0]+=a*r0.x; t1[u][1]+=a*r0.y; t1[u][2]+=a*r0.z; t1[u][3]+=a*r0.w;
      t1[u][4]+=a*r1.x; t1[u][5]+=a*r1.y; t1[u][6]+=a*r1.z; t1[u][7]+=a*r1.w;
      t1[u][8]+=a*r2.x; t1[u][9]+=a*r2.y; t1[u][10]+=a*r2.z; t1[u][11]+=a*r2.w;
      t1[u][12]+=a*r3.x; t1[u][13]+=a*r3.y; t1[u][14]+=a*r3.z; t1[u][15]+=a*r3.w;
    }
  }
}

// per-edge epilogue: out1 log_softmax store + layer-2 alpha accum
__device__ __forceinline__ void edge_epi(const float* ev, unsigned s, unsigned d, int e,
                                         const float* __restrict__ gw,
                                         const float* __restrict__ als2,
                                         const float* __restrict__ ald2,
                                         const float* __restrict__ h2,
                                         float* __restrict__ denom2, float* __restrict__ acc2,
                                         void* __restrict__ d_out, int f32in, int N){
  float m=fmaxf(fmaxf(ev[0],ev[1]),fmaxf(ev[2],ev[3]));
  float lse=m+logf(expf(ev[0]-m)+expf(ev[1]-m)+expf(ev[2]-m)+expf(ev[3]-m));
  if(f32in){
    float4 o; o.x=sanf(ev[0]-lse); o.y=sanf(ev[1]-lse); o.z=sanf(ev[2]-lse); o.w=sanf(ev[3]-lse);
    ((float4*)((float*)d_out+(size_t)2*N))[e]=o;
  }else{
    ull o = (ull)f2bu(sanf(ev[0]-lse))
          | ((ull)f2bu(sanf(ev[1]-lse))<<16)
          | ((ull)f2bu(sanf(ev[2]-lse))<<32)
          | ((ull)f2bu(sanf(ev[3]-lse))<<48);
    ((ull*)((bf16*)d_out+(size_t)2*N))[e]=o;
  }
  const float* s_ve2=gw+1020;
  float adot=ev[0]*s_ve2[0]+ev[1]*s_ve2[1]+ev[2]*s_ve2[2]+ev[3]*s_ve2[3];
  float a2=sanf(lrelu(als2[s]+ald2[d]+adot));
  float ex=expf(fminf(a2,80.f));
  float2 h2s=((const float2*)h2)[s];
  atomicAdd(&denom2[d],ex);
  atomicAdd(&acc2[(size_t)d*2+0],ex*h2s.x);
  atomicAdd(&acc2[(size_t)d*2+1],ex*h2s.y);
}

// common block-level stats reduction
__device__ __forceinline__ void stats_red(float c0,float c1,float c2,float c3,
                                          float* s_red, float* stats){
  int lane=threadIdx.x&63, wv=threadIdx.x>>6;
  c0=waveReduceSum(c0); c1=waveReduceSum(c1); c2=waveReduceSum(c2); c3=waveReduceSum(c3);
  __syncthreads();
  if(lane==0){ s_red[wv*4]=c0; s_red[wv*4+1]=c1; s_red[wv*4+2]=c2; s_red[wv*4+3]=c3; }
  __syncthreads();
  if(threadIdx.x==0){
    float a0=0,a1=0,a2=0,a3=0;
    for(int w=0;w<NT/64;w++){ a0+=s_red[w*4]; a1+=s_red[w*4+1]; a2+=s_red[w*4+2]; a3+=s_red[w*4+3]; }
    atomicAdd(&stats[3],a0); atomicAdd(&stats[4],a1); atomicAdd(&stats[5],a2); atomicAdd(&stats[6],a3);
  }
}

// ---------------- K6s: SPLIT edge MLP (uses u_s/u_d tables; L0 = 16 ld + 48 FMA + 16 add)
__global__ __launch_bounds__(NT,2) void k_edge2s(
    const int* __restrict__ idx, const void* __restrict__ ea,
    const float* __restrict__ us, const float* __restrict__ ud,
    const float* __restrict__ als2, const float* __restrict__ ald2,
    const float* __restrict__ gw,
    const float* __restrict__ h2,
    float* __restrict__ denom2, float* __restrict__ acc2,
    float* __restrict__ stats, void* __restrict__ d_out, int E, int N){
  const int f32in=((const int*)stats)[7];
  __shared__ float s_red[16];
  size_t base=(size_t)blockIdx.x*(NT*EPT)+threadIdx.x;
  int e[EPT]; bool v[EPT]; int es[EPT]; unsigned s[EPT], d[EPT];
#pragma unroll
  for(int u=0;u<EPT;u++){
    e[u]=(int)(base+(size_t)u*NT);
    v[u]=e[u]<E;
    es[u]=v[u]?e[u]:0;
    s[u]=clampi(idx[es[u]],N);
    d[u]=clampi(idx[(size_t)E+es[u]],N);
  }
  float t1[EPT][16];
  // t1 = u_s[s]  (contains b0 + h_s terms, reference prefix order)
#pragma unroll
  for(int u=0;u<EPT;u++){
    const float4* p=(const float4*)(us+(size_t)s[u]*16);
    float4 a0=p[0],a1=p[1],a2=p[2],a3=p[3];
    t1[u][0]=a0.x; t1[u][1]=a0.y; t1[u][2]=a0.z; t1[u][3]=a0.w;
    t1[u][4]=a1.x; t1[u][5]=a1.y; t1[u][6]=a1.z; t1[u][7]=a1.w;
    t1[u][8]=a2.x; t1[u][9]=a2.y; t1[u][10]=a2.z; t1[u][11]=a2.w;
    t1[u][12]=a3.x; t1[u][13]=a3.y; t1[u][14]=a3.z; t1[u][15]=a3.w;
  }
  // += ea rows (mw0 rows 16,17,18 at gw+256/+272/+288)
  {
    const float4* w16=(const float4*)(gw+256);
    const float4* w17=(const float4*)(gw+272);
    const float4* w18=(const float4*)(gw+288);
    float4 q0[3]={w16[0],w17[0],w18[0]}, q1[3]={w16[1],w17[1],w18[1]},
           q2[3]={w16[2],w17[2],w18[2]}, q3[3]={w16[3],w17[3],w18[3]};
#pragma unroll
    for(int u=0;u<EPT;u++){
      float e3[3];
      e3[0]=ld(ea,(size_t)es[u]*3+0,f32in);
      e3[1]=ld(ea,(size_t)es[u]*3+1,f32in);
      e3[2]=ld(ea,(size_t)es[u]*3+2,f32in);
#pragma unroll
      for(int k=0;k<3;k++){
        float a=e3[k];
        t1[u][0]+=a*q0[k].x; t1[u][1]+=a*q0[k].y; t1[u][2]+=a*q0[k].z; t1[u][3]+=a*q0[k].w;
        t1[u][4]+=a*q1[k].x; t1[u][5]+=a*q1[k].y; t1[u][6]+=a*q1[k].z; t1[u][7]+=a*q1[k].w;
        t1[u][8]+=a*q2[k].x; t1[u][9]+=a*q2[k].y; t1[u][10]+=a*q2[k].z; t1[u][11]+=a*q2[k].w;
        t1[u][12]+=a*q3[k].x; t1[u][13]+=a*q3[k].y; t1[u][14]+=a*q3[k].z; t1[u][15]+=a*q3[k].w;
      }
    }
  }
  // += u_d[d]
#pragma unroll
  for(int u=0;u<EPT;u++){
    const float4* p=(const float4*)(ud+(size_t)d[u]*16);
    float4 a0=p[0],a1=p[1],a2=p[2],a3=p[3];
    t1[u][0]+=a0.x; t1[u][1]+=a0.y; t1[u][2]+=a0.z; t1[u][3]+=a0.w;
    t1[u][4]+=a1.x; t1[u][5]+=a1.y; t1[u][6]+=a1.z; t1[u][7]+=a1.w;
    t1[u][8]+=a2.x; t1[u][9]+=a2.y; t1[u][10]+=a2.z; t1[u][11]+=a2.w;
    t1[u][12]+=a3.x; t1[u][13]+=a3.y; t1[u][14]+=a3.z; t1[u][15]+=a3.w;
  }
  float ev[EPT][4];
  mlp_tail4(t1,gw,ev);
  float c0=0.f,c1=0.f,c2=0.f,c3=0.f;
#pragma unroll
  for(int u=0;u<EPT;u++){
    if(v[u]){
      edge_epi(ev[u],s[u],d[u],e[u],gw,als2,ald2,h2,denom2,acc2,d_out,f32in,N);
      c0+=ev[u][0]; c1+=ev[u][1]; c2+=ev[u][2]; c3+=ev[u][3];
    }
  }
  stats_red(c0,c1,c2,c3,s_red,stats);
}

// ---------------- K6: fallback (R5): full MLP from h1 (EPT edges/thread)
__global__ __launch_bounds__(NT,1) void k_edge2(
    const int* __restrict__ idx, const void* __restrict__ ea,
    const bf16* __restrict__ h1,
    const float* __restrict__ als2, const float* __restrict__ ald2,
    const float* __restrict__ gw,
    const float* __restrict__ h2,
    float* __restrict__ denom2, float* __restrict__ acc2,
    float* __restrict__ stats, void* __restrict__ d_out, int E, int N){
  const int f32in=((const int*)stats)[7];
  __shared__ float s_red[16];
  size_t base=(size_t)blockIdx.x*(NT*EPT)+threadIdx.x;
  int e[EPT]; bool v[EPT]; int es[EPT]; unsigned s[EPT], d[EPT];
#pragma unroll
  for(int u=0;u<EPT;u++){
    e[u]=(int)(base+(size_t)u*NT);
    v[u]=e[u]<E;
    es[u]=v[u]?e[u]:0;
    s[u]=clampi(idx[es[u]],N);
    d[u]=clampi(idx[(size_t)E+es[u]],N);
  }
  float z[EPT][35];
#pragma unroll
  for(int u=0;u<EPT;u++){
    load_h1v(h1,s[u],z[u]);
    load_h1v(h1,d[u],z[u]+19);
    z[u][16]=ld(ea,(size_t)es[u]*3+0,f32in);
    z[u][17]=ld(ea,(size_t)es[u]*3+1,f32in);
    z[u][18]=ld(ea,(size_t)es[u]*3+2,f32in);
  }
  float t1[EPT][16];
  mlp_head_full4(z,gw,t1);
  float ev[EPT][4];
  mlp_tail4(t1,gw,ev);
  float c0=0.f,c1=0.f,c2=0.f,c3=0.f;
#pragma unroll
  for(int u=0;u<EPT;u++){
    if(v[u]){
      edge_epi(ev[u],s[u],d[u],e[u],gw,als2,ald2,h2,denom2,acc2,d_out,f32in,N);
      c0+=ev[u][0]; c1+=ev[u][1]; c2+=ev[u][2]; c3+=ev[u][3];
    }
  }
  stats_red(c0,c1,c2,c3,s_red,stats);
}

// ---------------- K7: fused self-loop fold + layer-2 epilogue + out0 log_softmax
__global__ __launch_bounds__(NT) void k_final(
    const float* __restrict__ stats, float invE,
    const float* __restrict__ als2, const float* __restrict__ ald2,
    const void* __restrict__ We2, const void* __restrict__ ae2,
    const float* __restrict__ h2,
    const float* __restrict__ denom2, const float* __restrict__ acc2,
    const void* __restrict__ bias2, void* __restrict__ d_out, int N){
  const int f32in=((const int*)stats)[7];
  __shared__ float s_ve2[4], s_b2[2];
  if(threadIdx.x<4)
    s_ve2[threadIdx.x]=ld(We2,threadIdx.x*2+0,f32in)*ld(ae2,0,f32in)
                      +ld(We2,threadIdx.x*2+1,f32in)*ld(ae2,1,f32in);
  if(threadIdx.x<2) s_b2[threadIdx.x]=ld(bias2,threadIdx.x,f32in);
  __syncthreads();
  int i=blockIdx.x*NT+threadIdx.x;
  if(i>=N) return;
  float adot=(stats[3]*s_ve2[0]+stats[4]*s_ve2[1]+stats[5]*s_ve2[2]+stats[6]*s_ve2[3])*invE;
  float self=lrelu(als2[i]+ald2[i]+adot);
  float ex=expf(fminf(self,80.f));
  float den=denom2[i]+ex;
  float inv=1.f/(den+1e-16f);
  float o0=(acc2[(size_t)i*2+0]+ex*h2[(size_t)i*2+0])*inv+s_b2[0];
  float o1=(acc2[(size_t)i*2+1]+ex*h2[(size_t)i*2+1])*inv+s_b2[1];
  float m=fmaxf(o0,o1);
  float lse=m+logf(expf(o0-m)+expf(o1-m));
  float r0=sanf(o0-lse), r1=sanf(o1-lse);
  if(f32in){
    float* o=(float*)d_out;
    o[(size_t)i*2+0]=r0; o[(size_t)i*2+1]=r1;
  }else{
    bf16* o=(bf16*)d_out;
    o[(size_t)i*2+0]=f2b(r0); o[(size_t)i*2+1]=f2b(r1);
  }
}

extern "C" void kernel_launch(void* const* d_in, const int* in_sizes, int n_in,
                              void* d_out, int out_size, void* d_ws, size_t ws_size,
                              hipStream_t stream){
  const void* x   =d_in[0];
  const void* ea  =d_in[1];
  const void* W1  =d_in[2];
  const void* as1 =d_in[3];
  const void* ad1 =d_in[4];
  const void* We1 =d_in[5];
  const void* ae1 =d_in[6];
  const void* b1  =d_in[7];
  const void* mw0 =d_in[8];
  const void* mb0 =d_in[9];
  const void* mw1 =d_in[10];
  const void* mb1 =d_in[11];
  const void* mw2 =d_in[12];
  const void* mb2 =d_in[13];
  const void* mw3 =d_in[14];
  const void* mb3 =d_in[15];
  const void* W2  =d_in[16];
  const void* as2 =d_in[17];
  const void* ad2 =d_in[18];
  const void* We2 =d_in[19];
  const void* ae2 =d_in[20];
  const void* bias2=d_in[21];
  const int*  idx =(const int*)d_in[22];

  int N=in_sizes[0]/4;
  int E=in_sizes[1]/3;
  float invE=1.f/(float)E;

  float*    F     =(float*)d_ws;
  float*    stats =F;                         // 8
  float*    als   =F+8;                       // N   (als2 aliases after gather1)
  float*    ald   =als+N;                     // N   (den2 aliases after gather1)
  float*    ald2  =ald+N;                     // N
  int*      rowc  =(int*)(ald2+N);            // N   (hist -> start -> end; then gw)
  bf16*     h1    =(bf16*)(rowc+N);           // 16N bf16 = 8N floats
  float*    h2    =(float*)(h1+(size_t)16*N); // 2N
  float*    acc2  =h2+(size_t)2*N;            // 2N
  float*    den2  =ald;
  float*    gw    =(float*)((((uintptr_t)rowc)+15)&~(uintptr_t)15);
  // u tables (split path): 16N floats each, past the 15N+8 high-water mark
  float*    u_s   =(float*)((((uintptr_t)(acc2+(size_t)2*N))+15)&~(uintptr_t)15);
  float*    u_d   =u_s+(size_t)16*N;
  size_t    need  =(size_t)((char*)(u_d+(size_t)16*N)-(char*)d_ws);
  int use_split   =(ws_size>=need)?1:0;

  ull* csr =(ull*)((char*)d_out+(size_t)4*N);
  int* bsum=(int*)((char*)d_out+(size_t)4*N);

  int NBn=(N+NT-1)/NT, nbE=(E+NT-1)/NT;
  int nbE4=(E+NT*EPT-1)/(NT*EPT);
  int nscan=in_sizes[0]*2; if(nscan>512) nscan=512;

  hipMemsetAsync(rowc,0,(size_t)N*sizeof(int),stream);
  k_probe  <<<1,64,0,stream>>>((const unsigned short*)x,nscan,stats);
  k_prep   <<<1024,NT,0,stream>>>(ea,idx,rowc,stats,E,N);
  k_node1  <<<NBn,NT,0,stream>>>(x,W1,as1,ad1,stats,als,ald,N);
  k_scan1  <<<NBn,NT,0,stream>>>(rowc,bsum,N);
  k_scan2  <<<1,1024,0,stream>>>(bsum,NBn);
  k_scan3  <<<NBn,NT,0,stream>>>(rowc,bsum,N);
  k_scatter<<<nbE,NT,0,stream>>>(idx,ea,We1,ae1,als,stats,rowc,csr,E,N);
  k_gather1<<<(N+15)/16,NT,0,stream>>>(csr,rowc,als,ald,x,W1,b1,W2,as2,ad2,We1,ae1,
                                       stats,invE,h1,h2,als,ald2,N);
  k_wprep  <<<1,NT,0,stream>>>(mw0,mb0,mw1,mb1,mw2,mb2,mw3,mb3,We2,ae2,stats,gw);
  hipMemsetAsync(den2,0,(size_t)N*sizeof(float),stream);
  hipMemsetAsync(acc2,0,(size_t)2*N*sizeof(float),stream);
  if(use_split){
    k_upre   <<<NBn,NT,0,stream>>>(h1,gw,u_s,u_d,N);
    k_edge2s <<<nbE4,NT,0,stream>>>(idx,ea,u_s,u_d,als,ald2,gw,h2,den2,acc2,stats,d_out,E,N);
  }else{
    k_edge2  <<<nbE4,NT,0,stream>>>(idx,ea,h1,als,ald2,gw,h2,den2,acc2,stats,d_out,E,N);
  }
  k_final  <<<NBn,NT,0,stream>>>(stats,invE,als,ald2,We2,ae2,h2,den2,acc2,bias2,d_out,N);
}